// Round 2
// 2692.568 us; speedup vs baseline: 2.3104x; 2.3104x over previous
//
#include <hip/hip_runtime.h>
#include <hip/hip_bf16.h>
#include <hip/hip_fp16.h>

#define BB   4
#define NN   16384
#define MM   1024
#define CC   256
#define KK   32
#define O1   128
#define FF   512
#define LTOT (BB*MM*KK)   // 131072
#define NSLOT 64
#define CH   16384
#define NCH2 (LTOT/CH)    // 8

typedef float f4 __attribute__((ext_vector_type(4)));
typedef short b8 __attribute__((ext_vector_type(8)));

__device__ __forceinline__ float bf2f(unsigned short u){
    return __uint_as_float(((unsigned int)u) << 16);
}
__device__ __forceinline__ float anyf(const void* p, size_t i, int f){
    if (f == 1) return bf2f(((const unsigned short*)p)[i]);
    if (f == 2) return __half2float(((const __half*)p)[i]);
    return ((const float*)p)[i];
}

// ---- dtype detector: 0=f32, 1=bf16, 2=fp16 ----
__global__ void k_det(const unsigned short* __restrict__ u, int n, int* __restrict__ flag){
    if (threadIdx.x != 0 || blockIdx.x != 0) return;
    int W = n < 64 ? n : 64;
    bool allz = true;
    for (int k = 0; k < W; k++) if (u[k]){ allz = false; break; }
    if (allz){ *flag = 1; return; }
    if (u[0] == 0x3F80u){ *flag = 1; return; }      // bf16 1.0
    if (u[0] == 0x3C00u){ *flag = 2; return; }      // fp16 1.0
    if (W >= 2){
        unsigned int f0 = ((unsigned int)u[1] << 16) | u[0];
        if (__uint_as_float(f0) == 1.0f){ *flag = 0; return; }  // f32 1.0
    }
    int ce = 0, co = 0, ne = 0, no_ = 0;
    for (int k = 0; k < W; k++){
        unsigned short x = u[k];
        float v = fabsf(bf2f(x));
        int sane = (x == 0) || (v >= 0.0009765625f && v <= 64.f);
        if (k & 1){ no_++; co += sane; } else { ne++; ce += sane; }
    }
    if (ce * 4 >= ne * 3){ *flag = 1; return; }
    if (co * 4 >= no_ * 3 && ce * 5 < ne * 2){ *flag = 0; return; }
    *flag = 2;
}

__global__ __launch_bounds__(256) void k_cvtf(const void* __restrict__ src,
                                              float* __restrict__ dst, int n,
                                              const int* __restrict__ flag){
    int t = blockIdx.x * 256 + threadIdx.x;
    if (t >= n) return;
    dst[t] = anyf(src, t, *flag);
}

// ---------------- Stage 1 ----------------
__global__ __launch_bounds__(256) void k_mlp1(const float* __restrict__ sw1,
                                              const float* __restrict__ feat,
                                              float* __restrict__ h1,
                                              float* __restrict__ stats1){
    int t = blockIdx.x * 256 + threadIdx.x;
    int m = t & (MM - 1);
    int o = (t >> 10) & (O1 - 1);
    int b = t >> 17;
    const float* fb = feat + (size_t)b * CC * MM + m;
    const float* w  = sw1 + o * CC;
    float acc = 0.f;
    #pragma unroll 8
    for (int c = 0; c < CC; c++) acc += w[c] * fb[(size_t)c * MM];
    h1[t] = acc;
    float s = acc, s2 = acc * acc;
    for (int off = 32; off; off >>= 1){ s += __shfl_down(s, off); s2 += __shfl_down(s2, off); }
    __shared__ float ls[8];
    int lane = threadIdx.x & 63, wid = threadIdx.x >> 6;
    if (lane == 0){ ls[wid] = s; ls[4 + wid] = s2; }
    __syncthreads();
    if (threadIdx.x == 0){
        atomicAdd(&stats1[2*o],   ls[0]+ls[1]+ls[2]+ls[3]);
        atomicAdd(&stats1[2*o+1], ls[4]+ls[5]+ls[6]+ls[7]);
    }
}

// ---------------- Stage 2 ----------------
__global__ __launch_bounds__(256) void k_bn1mlp2(const float* __restrict__ h1,
                                                 const float* __restrict__ stats1,
                                                 const float* __restrict__ sg1,
                                                 const float* __restrict__ sb1,
                                                 const float* __restrict__ sw2,
                                                 float* __restrict__ h2,
                                                 float* __restrict__ stats2){
    __shared__ float sc[O1], bi[O1];
    int tid = threadIdx.x;
    if (tid < O1){
        const float invn = 1.f / (BB * MM);
        float mean = stats1[2*tid] * invn;
        float var  = fmaxf(stats1[2*tid+1] * invn - mean * mean, 0.f);
        float rs   = 1.f / sqrtf(var + 1e-5f);
        float s    = rs * sg1[tid];
        float b_   = sb1[tid] - mean * s;
        if (!isfinite(s) || !isfinite(b_)){ s = 1.f; b_ = 0.f; }
        sc[tid] = s; bi[tid] = b_;
    }
    __syncthreads();
    int t = blockIdx.x * 256 + tid;
    int m = t & (MM - 1);
    int r = t >> 10; int o2 = r % 3; int b = r / 3;
    const float* hb = h1 + (size_t)b * O1 * MM + m;
    const float* w  = sw2 + o2 * O1;
    float acc = 0.f;
    #pragma unroll 8
    for (int c = 0; c < O1; c++){
        float v = hb[(size_t)c * MM] * sc[c] + bi[c];
        v = v > 0.f ? v : 0.f;
        acc += w[c] * v;
    }
    h2[t] = acc;
    float s = acc, s2 = acc * acc;
    for (int off = 32; off; off >>= 1){ s += __shfl_down(s, off); s2 += __shfl_down(s2, off); }
    __shared__ float ls[8];
    int lane = tid & 63, wid = tid >> 6;
    if (lane == 0){ ls[wid] = s; ls[4 + wid] = s2; }
    __syncthreads();
    if (tid == 0){
        atomicAdd(&stats2[2*o2],   ls[0]+ls[1]+ls[2]+ls[3]);
        atomicAdd(&stats2[2*o2+1], ls[4]+ls[5]+ls[6]+ls[7]);
    }
}

__global__ void k_fin2(const float* __restrict__ stats2, const float* __restrict__ sg2,
                       const float* __restrict__ sb2, float* __restrict__ scb2){
    int t = threadIdx.x;
    if (t < 3){
        const float invn = 1.f / (BB * MM);
        float mean = stats2[2*t] * invn;
        float var  = fmaxf(stats2[2*t+1] * invn - mean * mean, 0.f);
        float rs   = 1.f / sqrtf(var + 1e-5f);
        float s    = rs * sg2[t];
        float b    = sb2[t] - mean * s;
        if (!isfinite(s) || !isfinite(b)){ s = 1.f; b = 0.f; }
        scb2[t] = s; scb2[4 + t] = b;
    }
}

// ---------------- ball query ----------------
__global__ __launch_bounds__(256) void k_ballq(const float* __restrict__ fxyz,
                                               const float* __restrict__ h2,
                                               const float* __restrict__ scb2,
                                               const float* __restrict__ bxyz,
                                               float* __restrict__ nxyz,
                                               int* __restrict__ idxbuf){
    int q    = blockIdx.x * 4 + (threadIdx.x >> 6);
    int lane = threadIdx.x & 63;
    int b = q >> 10, m = q & (MM - 1);
    float nx[3];
    #pragma unroll
    for (int c = 0; c < 3; c++){
        float v = h2[((size_t)b * 3 + c) * MM + m] * scb2[c] + scb2[4 + c];
        v = v > 0.f ? v : 0.f;
        nx[c] = fxyz[(size_t)q * 3 + c] + v;
    }
    if (lane == 0){
        nxyz[q*3+0] = nx[0]; nxyz[q*3+1] = nx[1]; nxyz[q*3+2] = nx[2];
    }
    const float* bx = bxyz + (size_t)b * NN * 3;
    int have = 0, firstj = 0;
    int* out = idxbuf + (size_t)q * KK;
    for (int j0 = 0; j0 < NN && have < KK; j0 += 64){
        int j = j0 + lane;
        float dx = bx[j*3+0] - nx[0];
        float dy = bx[j*3+1] - nx[1];
        float dz = bx[j*3+2] - nx[2];
        float d2 = dx*dx + dy*dy + dz*dz;
        bool pred = d2 < 1.0f;
        unsigned long long mask = __ballot(pred);
        if (mask){
            if (have == 0) firstj = j0 + (__ffsll((unsigned long long)mask) - 1);
            if (pred){
                int rank = __popcll(mask & ((1ull << lane) - 1ull));
                int pos = have + rank;
                if (pos < KK) out[pos] = j;
            }
            have += (int)__popcll(mask);
        }
    }
    if (have < KK){
        int fill = (have > 0) ? firstj : 0;
        for (int p = have + lane; p < KK; p += 64) out[p] = fill;
    }
}

// ---------------- idx2 / xyzdiff ----------------
__global__ __launch_bounds__(256) void k_xyzd(const int* __restrict__ idxbuf,
                                              const float* __restrict__ bxyz,
                                              const float* __restrict__ nxyz,
                                              int* __restrict__ idx2,
                                              float4* __restrict__ xyzd){
    int l = blockIdx.x * 256 + threadIdx.x;
    int b = l >> 15;
    int q = l >> 5;
    int j = idxbuf[l];
    idx2[l] = b * NN + j;
    const float* p = bxyz + ((size_t)b * NN + j) * 3;
    xyzd[l] = make_float4(p[0] - nxyz[q*3+0], p[1] - nxyz[q*3+1], p[2] - nxyz[q*3+2], 0.f);
}

// ---------------- transpose (B,C,N) -> (B,N,C) f32, flag-aware ----------------
__global__ __launch_bounds__(256) void k_transp(const void* __restrict__ bfv,
                                                const int* __restrict__ flag,
                                                float* __restrict__ ft){
    __shared__ float tile[32][33];
    int f = *flag;
    int bid = blockIdx.x;
    int nt = bid & 511;
    int ct = (bid >> 9) & 7;
    int b  = bid >> 12;
    int tx = threadIdx.x & 31, ty = threadIdx.x >> 5;
    size_t base = ((size_t)b * CC + ct * 32) * NN + nt * 32;
    #pragma unroll
    for (int r = 0; r < 32; r += 8)
        tile[ty + r][tx] = anyf(bfv, base + (size_t)(ty + r) * NN + tx, f);
    __syncthreads();
    float* dst = ft + ((size_t)b * NN + nt * 32) * CC + ct * 32;
    #pragma unroll
    for (int r = 0; r < 32; r += 8) dst[(size_t)(ty + r) * CC + tx] = tile[tx][ty + r];
}

// ---------------- weight prep ----------------
__global__ void k_wprep(const float* __restrict__ w1, float* __restrict__ w1p,
                        float4* __restrict__ w1xp){
    int t = blockIdx.x * 256 + threadIdx.x;
    int o = t >> 8, c = t & 255;
    w1p[t] = w1[o * 259 + 3 + c];
    if (t < 512) w1xp[t] = make_float4(w1[t*259], w1[t*259+1], w1[t*259+2], 0.f);
}

// ---------------- MFMA split-bf16 GEMM ----------------
// Y[l][o] = sum_c A[o][c] * X[l][c]   (optionally X pre-transformed by BN+ReLU via scb)
// f32 accuracy via hi/lo bf16 split: a*b ~= ah*bh + ah*bl + al*bh  (error ~2^-16)
// Tile 128(o) x 128(l) x 32(c). 256 threads = 4 waves, each wave 64x64 (4x4 frags 16x16).
__device__ __forceinline__ void split4(float x, float y, float z_, float w_,
                                       unsigned &h0, unsigned &h1,
                                       unsigned &lo0, unsigned &lo1){
    unsigned ux = __float_as_uint(x), uy = __float_as_uint(y);
    unsigned uz = __float_as_uint(z_), uw = __float_as_uint(w_);
    unsigned hx = ux & 0xFFFF0000u, hy = uy & 0xFFFF0000u;
    unsigned hz = uz & 0xFFFF0000u, hw = uw & 0xFFFF0000u;
    h0 = (hx >> 16) | hy;
    h1 = (hz >> 16) | hw;
    float rx = x  - __uint_as_float(hx);
    float ry = y  - __uint_as_float(hy);
    float rz = z_ - __uint_as_float(hz);
    float rw = w_ - __uint_as_float(hw);
    lo0 = (__float_as_uint(rx) >> 16) | (__float_as_uint(ry) & 0xFFFF0000u);
    lo1 = (__float_as_uint(rz) >> 16) | (__float_as_uint(rw) & 0xFFFF0000u);
}

__global__ __launch_bounds__(256) void k_gemm(const float* __restrict__ A,
                                              const float* __restrict__ X,
                                              int Cs,
                                              const float* __restrict__ scb,
                                              float* __restrict__ Y,
                                              double* __restrict__ stats){
    // LDS: fragment-linear layout [frag(8)][lane(64)][8 bf16] per buffer.
    // bytes: Ahi [0,8K) Alo [8K,16K) Xhi [16K,24K) Xlo [24K,32K)
    __shared__ short lds[16384];
    char* ldsb = (char*)lds;

    const int tid  = threadIdx.x;
    const int lane = tid & 63;
    const int w    = tid >> 6;
    const int wo   = (w >> 1) * 64;
    const int wl   = (w & 1) * 64;

    // XCD-aware swizzle (gridDim.x is a multiple of 8: 2048 or 512)
    int bid = blockIdx.x;
    {
        int cpx = gridDim.x >> 3;
        bid = (bid & 7) * cpx + (bid >> 3);
    }
    const int o0 = (bid & 3) * 128;       // FF/128 == 4 o-tiles
    const int l0 = (bid >> 2) * 128;

    // staging mapping: thread t handles rows (t>>3)+32*i (i=0..3), cols q*8+h*4..+3
    const int o_loc  = tid >> 3;          // 0..31
    const int q      = (tid & 7) >> 1;    // 0..3
    const int h      = tid & 1;           // 0..1
    const int colOff = q * 8 + h * 4;
    const int slot   = (o_loc & 15) | (q << 4);
    const int wbase  = ((o_loc >> 4) * 1024) + slot * 16 + h * 8;  // +2048 per issue
    const int roff   = lane * 16;         // fragment read offset (conflict-free b128)

    const float* Ap = A + (size_t)(o0 + o_loc) * Cs + colOff;
    const float* Xp = X + (size_t)(l0 + o_loc) * Cs + colOff;

    f4 acc[4][4];
    #pragma unroll
    for (int i = 0; i < 4; i++)
        #pragma unroll
        for (int j = 0; j < 4; j++)
            acc[i][j] = f4{0.f, 0.f, 0.f, 0.f};

    float4 ra[4], rx[4];
    #pragma unroll
    for (int i = 0; i < 4; i++){
        ra[i] = *(const float4*)(Ap + (size_t)(32 * i) * Cs);
        rx[i] = *(const float4*)(Xp + (size_t)(32 * i) * Cs);
    }

    for (int c0 = 0; c0 < Cs; c0 += 32){
        // convert staged regs (apply BN+ReLU to X if scb)
        unsigned ah0[4], ah1[4], aL0[4], aL1[4];
        unsigned xh0[4], xh1[4], xL0[4], xL1[4];
        float4 sc4, bi4;
        if (scb){
            sc4 = *(const float4*)(scb + c0 + colOff);
            bi4 = *(const float4*)(scb + Cs + c0 + colOff);
        }
        #pragma unroll
        for (int i = 0; i < 4; i++){
            split4(ra[i].x, ra[i].y, ra[i].z, ra[i].w, ah0[i], ah1[i], aL0[i], aL1[i]);
            float vx = rx[i].x, vy = rx[i].y, vz = rx[i].z, vw = rx[i].w;
            if (scb){
                vx = fmaxf(vx * sc4.x + bi4.x, 0.f);
                vy = fmaxf(vy * sc4.y + bi4.y, 0.f);
                vz = fmaxf(vz * sc4.z + bi4.z, 0.f);
                vw = fmaxf(vw * sc4.w + bi4.w, 0.f);
            }
            split4(vx, vy, vz, vw, xh0[i], xh1[i], xL0[i], xL1[i]);
        }
        __syncthreads();   // prev iteration's fragment reads done
        #pragma unroll
        for (int i = 0; i < 4; i++){
            int off = wbase + i * 2048;
            *(uint2*)(ldsb + off)          = make_uint2(ah0[i], ah1[i]);
            *(uint2*)(ldsb + 8192  + off)  = make_uint2(aL0[i], aL1[i]);
            *(uint2*)(ldsb + 16384 + off)  = make_uint2(xh0[i], xh1[i]);
            *(uint2*)(ldsb + 24576 + off)  = make_uint2(xL0[i], xL1[i]);
        }
        __syncthreads();
        // prefetch next K-step (latency hides under MFMA below)
        if (c0 + 32 < Cs){
            #pragma unroll
            for (int i = 0; i < 4; i++){
                ra[i] = *(const float4*)(Ap + (size_t)(32 * i) * Cs + (c0 + 32));
                rx[i] = *(const float4*)(Xp + (size_t)(32 * i) * Cs + (c0 + 32));
            }
        }
        // MFMA: 4x4 frags x 3 split terms
        b8 bhf[4], blf[4];
        #pragma unroll
        for (int ni = 0; ni < 4; ni++){
            int f = (wl >> 4) + ni;
            bhf[ni] = *(const b8*)(ldsb + 16384 + f * 1024 + roff);
            blf[ni] = *(const b8*)(ldsb + 24576 + f * 1024 + roff);
        }
        #pragma unroll
        for (int mi = 0; mi < 4; mi++){
            int f = (wo >> 4) + mi;
            b8 ahf = *(const b8*)(ldsb + f * 1024 + roff);
            b8 alf = *(const b8*)(ldsb + 8192 + f * 1024 + roff);
            #pragma unroll
            for (int ni = 0; ni < 4; ni++){
                acc[mi][ni] = __builtin_amdgcn_mfma_f32_16x16x32_bf16(ahf, bhf[ni], acc[mi][ni], 0, 0, 0);
                acc[mi][ni] = __builtin_amdgcn_mfma_f32_16x16x32_bf16(ahf, blf[ni], acc[mi][ni], 0, 0, 0);
                acc[mi][ni] = __builtin_amdgcn_mfma_f32_16x16x32_bf16(alf, bhf[ni], acc[mi][ni], 0, 0, 0);
            }
        }
    }

    // epilogue: D row (o) = 4*(lane>>4)+r, col (l) = lane&15   [m89-verified C/D layout]
    if (Y){
        #pragma unroll
        for (int mi = 0; mi < 4; mi++){
            #pragma unroll
            for (int ni = 0; ni < 4; ni++){
                int o = o0 + wo + mi * 16 + 4 * (lane >> 4);
                int l = l0 + wl + ni * 16 + (lane & 15);
                *(float4*)(Y + (size_t)l * FF + o) =
                    make_float4(acc[mi][ni][0], acc[mi][ni][1], acc[mi][ni][2], acc[mi][ni][3]);
            }
        }
    }
    if (stats){
        int slot_s = blockIdx.x & (NSLOT - 1);
        double* sp = stats + (size_t)slot_s * FF * 2;
        #pragma unroll
        for (int mi = 0; mi < 4; mi++){
            float s1[4] = {0,0,0,0}, s2[4] = {0,0,0,0};
            #pragma unroll
            for (int ni = 0; ni < 4; ni++){
                #pragma unroll
                for (int r = 0; r < 4; r++){
                    float v = acc[mi][ni][r];
                    s1[r] += v; s2[r] += v * v;
                }
            }
            #pragma unroll
            for (int off = 8; off; off >>= 1){
                #pragma unroll
                for (int r = 0; r < 4; r++){
                    s1[r] += __shfl_down(s1[r], off, 16);
                    s2[r] += __shfl_down(s2[r], off, 16);
                }
            }
            if ((lane & 15) == 0){
                int o = o0 + wo + mi * 16 + 4 * (lane >> 4);
                #pragma unroll
                for (int r = 0; r < 4; r++){
                    atomicAdd(&sp[2 * (o + r)],     (double)s1[r]);
                    atomicAdd(&sp[2 * (o + r) + 1], (double)s2[r]);
                }
            }
        }
    }
}

// ---------------- finalize BN ----------------
__global__ void k_finL(const double* __restrict__ stats, const float* __restrict__ g,
                       const float* __restrict__ bt, float* __restrict__ scb){
    int o = blockIdx.x * 256 + threadIdx.x;
    double s = 0.0, s2 = 0.0;
    for (int k = 0; k < NSLOT; k++){
        s  += stats[((size_t)k * FF + o) * 2];
        s2 += stats[((size_t)k * FF + o) * 2 + 1];
    }
    double mean = s / (double)LTOT;
    double var  = s2 / (double)LTOT - mean * mean;
    if (!(var > 0.0)) var = 0.0;
    double rs = 1.0 / sqrt(var + 1e-5);
    double sc = rs * (double)g[o];
    double bi = (double)bt[o] - mean * sc;
    float scf = (float)sc, bif = (float)bi;
    if (!isfinite(scf) || !isfinite(bif)){ scf = 1.f; bif = 0.f; }
    scb[o] = scf;
    scb[FF + o] = bif;
}

// ---------------- y1 stats ----------------
__global__ __launch_bounds__(256) void k_y1stats(const float* __restrict__ z,
                                                 const int* __restrict__ idx2,
                                                 const float4* __restrict__ xyzd,
                                                 const float4* __restrict__ w1xp,
                                                 double* __restrict__ stats){
    int tid = threadIdx.x, bid = blockIdx.x;
    int o1 = tid, o2 = tid + 256;
    float4 wa = w1xp[o1], wb = w1xp[o2];
    double s1a=0, s2a=0, s1b=0, s2b=0;
    for (int p = 0; p < LTOT/2048; p++){
        int l = bid + p * 2048;
        int r = idx2[l];
        float4 d = xyzd[l];
        const float* zr = z + (size_t)r * FF;
        float ya = zr[o1] + d.x*wa.x + d.y*wa.y + d.z*wa.z;
        float yb = zr[o2] + d.x*wb.x + d.y*wb.y + d.z*wb.z;
        s1a += ya; s2a += (double)ya*ya;
        s1b += yb; s2b += (double)yb*yb;
    }
    int slot = bid & (NSLOT - 1);
    double* sp = stats + (size_t)slot * FF * 2;
    atomicAdd(&sp[2*o1],   s1a); atomicAdd(&sp[2*o1+1], s2a);
    atomicAdd(&sp[2*o2],   s1b); atomicAdd(&sp[2*o2+1], s2b);
}

// ---------------- materialize X1 chunk ----------------
__global__ __launch_bounds__(256) void k_y1mat(const float* __restrict__ z,
                                               const int* __restrict__ idx2,
                                               const float4* __restrict__ xyzd,
                                               const float4* __restrict__ w1xp,
                                               const float* __restrict__ scb,
                                               float* __restrict__ t1, int L0){
    int tid = threadIdx.x, bid = blockIdx.x;
    int o1 = tid, o2 = tid + 256;
    float4 wa = w1xp[o1], wb = w1xp[o2];
    float sa = scb[o1], ba = scb[FF+o1], sb = scb[o2], bb = scb[FF+o2];
    for (int p = 0; p < CH/1024; p++){
        int ll = bid + p * 1024;
        int l  = L0 + ll;
        int r = idx2[l];
        float4 d = xyzd[l];
        const float* zr = z + (size_t)r * FF;
        float ya = zr[o1] + d.x*wa.x + d.y*wa.y + d.z*wa.z;
        float yb = zr[o2] + d.x*wb.x + d.y*wb.y + d.z*wb.z;
        t1[(size_t)ll * FF + o1] = fmaxf(ya * sa + ba, 0.f);
        t1[(size_t)ll * FF + o2] = fmaxf(yb * sb + bb, 0.f);
    }
}

// ---------------- final max: out[q,o] = max_k relu(bn3(y3)) — FLOAT32 OUTPUT ----------------
__global__ __launch_bounds__(256) void k_maxout(const float* __restrict__ y3,
                                                const float* __restrict__ scb,
                                                float* __restrict__ out,
                                                int q0){
    int qr = blockIdx.x;
    int q = q0 + qr;
    int o = threadIdx.x;
    const float* yb = y3 + (size_t)qr * KK * FF;
    #pragma unroll
    for (int rep = 0; rep < 2; rep++, o += 256){
        float sc = scb[o], bi = scb[FF + o];
        float mx = 0.f;
        for (int k = 0; k < KK; k++){
            float v = fmaxf(yb[(size_t)k * FF + o] * sc + bi, 0.f);
            mx = fmaxf(mx, v);
        }
        out[(size_t)q * FF + o] = mx;
    }
}

// ---------------- stage diagnostics (float sentinel, fires only on unhealthy) ----------------
__global__ __launch_bounds__(256) void k_diag(const float* __restrict__ ff,
                                              const float* __restrict__ w1f,
                                              const float* __restrict__ featT,
                                              const float* __restrict__ z,
                                              const float* __restrict__ xyzdf,
                                              const float* __restrict__ scb1,
                                              const float* __restrict__ scbL2,
                                              const float* __restrict__ scbL3,
                                              const float* __restrict__ y3,
                                              float* __restrict__ out){
    __shared__ float red[4];
    int tid = threadIdx.x;
    int bad = 0, isn = 0;
    const float* arr[9] = {ff, w1f, featT, z, xyzdf, scb1, scbL2, scbL3, y3};
    const int   len[9] = {4096, 4096, 8192, 8192, 4096, 1024, 1024, 1024, 8192};
    for (int k = 0; k < 9; k++){
        float s = 0.f;
        const float* a = arr[k];
        for (int i = tid; i < len[k]; i += 256) s += fabsf(a[i]);
        for (int off = 32; off; off >>= 1) s += __shfl_down(s, off);
        if ((tid & 63) == 0) red[tid >> 6] = s;
        __syncthreads();
        float t = red[0] + red[1] + red[2] + red[3];
        __syncthreads();
        if (bad == 0 && !(t > 1e-6f && t < 1e15f)){
            bad = k + 1;
            isn = isfinite(t) ? 0 : 1;
        }
    }
    if (tid == 0 && bad) out[0] = 512.f * bad + 256.f * isn;
}

extern "C" void kernel_launch(void* const* d_in, const int* in_sizes, int n_in,
                              void* d_out, int out_size, void* d_ws, size_t ws_size,
                              hipStream_t stream) {
    static const int NSZ[19] = {12288, 1048576, 196608, 16777216, 32768, 128, 128,
                                384, 3, 3, 132608, 512, 512, 262144, 512, 512,
                                262144, 512, 512};
    float* out = (float*)d_out;   // OUTPUT IS FLOAT32 (reference returns jnp.float32)

    char* w = (char*)d_ws;
    size_t off = 0;
    auto take = [&](size_t bytes)->size_t{
        size_t r = off; off += (bytes + 255) & ~(size_t)255; return r;
    };
    size_t o_stats1  = take(256 * 4);
    size_t o_stats2  = take(8 * 4);
    size_t o_statsA  = take((size_t)NSLOT * FF * 2 * 8);
    size_t o_statsL2 = take((size_t)NSLOT * FF * 2 * 8);
    size_t o_statsL3 = take((size_t)NSLOT * FF * 2 * 8);
    size_t zero_end  = off;
    size_t o_flags   = take(19 * 4);
    size_t o_cv[19];
    for (int i = 0; i < 19; i++){
        if (i == 3){ o_cv[i] = 0; continue; }
        o_cv[i] = take((size_t)NSZ[i] * 4);
    }
    size_t o_scb2    = take(8 * 4);
    size_t o_scb1    = take(FF * 2 * 4);
    size_t o_scbL2   = take(FF * 2 * 4);
    size_t o_scbL3   = take(FF * 2 * 4);
    size_t o_h1      = take((size_t)BB * O1 * MM * 4);
    size_t o_h2      = take((size_t)BB * 3 * MM * 4);
    size_t o_nxyz    = take((size_t)BB * MM * 3 * 4);
    size_t o_idx     = take((size_t)LTOT * 4);
    size_t o_idx2    = take((size_t)LTOT * 4);
    size_t o_xyzd    = take((size_t)LTOT * 16);
    size_t o_w1p     = take((size_t)FF * CC * 4);
    size_t o_w1xp    = take((size_t)FF * 16);
    size_t o_featT   = take((size_t)BB * NN * CC * 4);
    size_t o_t1      = o_featT;
    size_t o_t2      = o_featT + (size_t)CH * FF * 4;
    size_t o_z       = take((size_t)BB * NN * FF * 4);
    (void)ws_size; (void)n_in; (void)in_sizes; (void)out_size;

    float*  stats1  = (float*) (w + o_stats1);
    float*  stats2  = (float*) (w + o_stats2);
    double* statsA  = (double*)(w + o_statsA);
    double* statsL2 = (double*)(w + o_statsL2);
    double* statsL3 = (double*)(w + o_statsL3);
    int*    flags   = (int*)   (w + o_flags);
    float*  scb2    = (float*) (w + o_scb2);
    float*  scb1    = (float*) (w + o_scb1);
    float*  scbL2   = (float*) (w + o_scbL2);
    float*  scbL3   = (float*) (w + o_scbL3);
    float*  h1      = (float*) (w + o_h1);
    float*  h2      = (float*) (w + o_h2);
    float*  nxyz    = (float*) (w + o_nxyz);
    int*    idxbuf  = (int*)   (w + o_idx);
    int*    idx2    = (int*)   (w + o_idx2);
    float4* xyzd    = (float4*)(w + o_xyzd);
    float*  w1p     = (float*) (w + o_w1p);
    float4* w1xp    = (float4*)(w + o_w1xp);
    float*  featT   = (float*) (w + o_featT);
    float*  t1      = (float*) (w + o_t1);
    float*  t2      = (float*) (w + o_t2);
    float*  z       = (float*) (w + o_z);

    hipMemsetAsync(w, 0, zero_end, stream);

    float* cv[19];
    for (int i = 0; i < 19; i++){
        k_det<<<1, 64, 0, stream>>>((const unsigned short*)d_in[i], NSZ[i], flags + i);
        if (i == 3){ cv[i] = nullptr; continue; }
        cv[i] = (float*)(w + o_cv[i]);
    }
    for (int i = 0; i < 19; i++){
        if (i == 3) continue;
        k_cvtf<<<(NSZ[i] + 255) / 256, 256, 0, stream>>>(d_in[i], cv[i], NSZ[i], flags + i);
    }
    float* fx = cv[0], *ffp = cv[1], *bx = cv[2];
    float* sw1f = cv[4], *sg1f = cv[5], *sb1f = cv[6];
    float* sw2f = cv[7], *sg2f = cv[8], *sb2f = cv[9];
    float* w1f = cv[10], *g1f = cv[11], *b1f = cv[12];
    float* w2f = cv[13], *g2f = cv[14], *b2f = cv[15];
    float* w3f = cv[16], *g3f = cv[17], *b3f = cv[18];

    k_mlp1   <<<2048, 256, 0, stream>>>(sw1f, ffp, h1, stats1);
    k_bn1mlp2<<<48,   256, 0, stream>>>(h1, stats1, sg1f, sb1f, sw2f, h2, stats2);
    k_fin2   <<<1,    64,  0, stream>>>(stats2, sg2f, sb2f, scb2);
    k_ballq  <<<BB*MM/4, 256, 0, stream>>>(fx, h2, scb2, bx, nxyz, idxbuf);
    k_xyzd   <<<LTOT/256, 256, 0, stream>>>(idxbuf, bx, nxyz, idx2, xyzd);
    k_transp <<<BB*(CC/32)*(NN/32), 256, 0, stream>>>(d_in[3], flags + 3, featT);
    k_wprep  <<<512, 256, 0, stream>>>(w1f, w1p, w1xp);

    // z = featT @ w1p^T  : (65536 x 256) x (512 x 256)^T  -> 65536 x 512
    k_gemm <<<4 * (BB*NN/128), 256, 0, stream>>>(w1p, featT, CC, nullptr, z, nullptr);

    k_y1stats<<<2048, 256, 0, stream>>>(z, idx2, xyzd, w1xp, statsA);
    k_finL  <<<2, 256, 0, stream>>>(statsA, g1f, b1f, scb1);

    const int G = 4 * (CH/128);
    for (int c = 0; c < NCH2; c++){
        k_y1mat<<<1024, 256, 0, stream>>>(z, idx2, xyzd, w1xp, scb1, t1, c*CH);
        k_gemm <<<G, 256, 0, stream>>>(w2f, t1, FF, nullptr, nullptr, statsL2);
    }
    k_finL <<<2, 256, 0, stream>>>(statsL2, g2f, b2f, scbL2);
    for (int c = 0; c < NCH2; c++){
        k_y1mat<<<1024, 256, 0, stream>>>(z, idx2, xyzd, w1xp, scb1, t1, c*CH);
        k_gemm <<<G, 256, 0, stream>>>(w2f, t1, FF, nullptr, t2, nullptr);
        k_gemm <<<G, 256, 0, stream>>>(w3f, t2, FF, scbL2, nullptr, statsL3);
    }
    k_finL <<<2, 256, 0, stream>>>(statsL3, g3f, b3f, scbL3);
    for (int c = 0; c < NCH2; c++){
        k_y1mat<<<1024, 256, 0, stream>>>(z, idx2, xyzd, w1xp, scb1, t1, c*CH);
        k_gemm <<<G, 256, 0, stream>>>(w2f, t1, FF, nullptr, t2, nullptr);
        k_gemm <<<G, 256, 0, stream>>>(w3f, t2, FF, scbL2, t1, nullptr);
        k_maxout<<<CH/KK, 256, 0, stream>>>(t1, scbL3, out, c*(CH/KK));
    }

    // diagnostics: float sentinel into out[0] on first unhealthy stage; no-op when healthy
    k_diag<<<1, 256, 0, stream>>>(ffp, w1f, featT, z, (const float*)xyzd,
                                  scb1, scbL2, scbL3, t1, out);
}

// Round 3
// 2495.904 us; speedup vs baseline: 2.4925x; 1.0788x over previous
//
#include <hip/hip_runtime.h>
#include <hip/hip_bf16.h>
#include <hip/hip_fp16.h>

#define BB   4
#define NN   16384
#define MM   1024
#define CC   256
#define KK   32
#define O1   128
#define FF   512
#define LTOT (BB*MM*KK)   // 131072
#define NSLOT 64
#define CH   16384
#define NCH2 (LTOT/CH)    // 8

typedef float f4 __attribute__((ext_vector_type(4)));
typedef short b8 __attribute__((ext_vector_type(8)));

__device__ __forceinline__ float bf2f(unsigned short u){
    return __uint_as_float(((unsigned int)u) << 16);
}
__device__ __forceinline__ float anyf(const void* p, size_t i, int f){
    if (f == 1) return bf2f(((const unsigned short*)p)[i]);
    if (f == 2) return __half2float(((const __half*)p)[i]);
    return ((const float*)p)[i];
}

// ---- dtype detector: 0=f32, 1=bf16, 2=fp16 ----
__global__ void k_det(const unsigned short* __restrict__ u, int n, int* __restrict__ flag){
    if (threadIdx.x != 0 || blockIdx.x != 0) return;
    int W = n < 64 ? n : 64;
    bool allz = true;
    for (int k = 0; k < W; k++) if (u[k]){ allz = false; break; }
    if (allz){ *flag = 1; return; }
    if (u[0] == 0x3F80u){ *flag = 1; return; }      // bf16 1.0
    if (u[0] == 0x3C00u){ *flag = 2; return; }      // fp16 1.0
    if (W >= 2){
        unsigned int f0 = ((unsigned int)u[1] << 16) | u[0];
        if (__uint_as_float(f0) == 1.0f){ *flag = 0; return; }  // f32 1.0
    }
    int ce = 0, co = 0, ne = 0, no_ = 0;
    for (int k = 0; k < W; k++){
        unsigned short x = u[k];
        float v = fabsf(bf2f(x));
        int sane = (x == 0) || (v >= 0.0009765625f && v <= 64.f);
        if (k & 1){ no_++; co += sane; } else { ne++; ce += sane; }
    }
    if (ce * 4 >= ne * 3){ *flag = 1; return; }
    if (co * 4 >= no_ * 3 && ce * 5 < ne * 2){ *flag = 0; return; }
    *flag = 2;
}

__global__ __launch_bounds__(256) void k_cvtf(const void* __restrict__ src,
                                              float* __restrict__ dst, int n,
                                              const int* __restrict__ flag){
    int t = blockIdx.x * 256 + threadIdx.x;
    if (t >= n) return;
    dst[t] = anyf(src, t, *flag);
}

// ---------------- Stage 1 ----------------
__global__ __launch_bounds__(256) void k_mlp1(const float* __restrict__ sw1,
                                              const float* __restrict__ feat,
                                              float* __restrict__ h1,
                                              float* __restrict__ stats1){
    int t = blockIdx.x * 256 + threadIdx.x;
    int m = t & (MM - 1);
    int o = (t >> 10) & (O1 - 1);
    int b = t >> 17;
    const float* fb = feat + (size_t)b * CC * MM + m;
    const float* w  = sw1 + o * CC;
    float acc = 0.f;
    #pragma unroll 8
    for (int c = 0; c < CC; c++) acc += w[c] * fb[(size_t)c * MM];
    h1[t] = acc;
    float s = acc, s2 = acc * acc;
    for (int off = 32; off; off >>= 1){ s += __shfl_down(s, off); s2 += __shfl_down(s2, off); }
    __shared__ float ls[8];
    int lane = threadIdx.x & 63, wid = threadIdx.x >> 6;
    if (lane == 0){ ls[wid] = s; ls[4 + wid] = s2; }
    __syncthreads();
    if (threadIdx.x == 0){
        atomicAdd(&stats1[2*o],   ls[0]+ls[1]+ls[2]+ls[3]);
        atomicAdd(&stats1[2*o+1], ls[4]+ls[5]+ls[6]+ls[7]);
    }
}

// ---------------- Stage 2 ----------------
__global__ __launch_bounds__(256) void k_bn1mlp2(const float* __restrict__ h1,
                                                 const float* __restrict__ stats1,
                                                 const float* __restrict__ sg1,
                                                 const float* __restrict__ sb1,
                                                 const float* __restrict__ sw2,
                                                 float* __restrict__ h2,
                                                 float* __restrict__ stats2){
    __shared__ float sc[O1], bi[O1];
    int tid = threadIdx.x;
    if (tid < O1){
        const float invn = 1.f / (BB * MM);
        float mean = stats1[2*tid] * invn;
        float var  = fmaxf(stats1[2*tid+1] * invn - mean * mean, 0.f);
        float rs   = 1.f / sqrtf(var + 1e-5f);
        float s    = rs * sg1[tid];
        float b_   = sb1[tid] - mean * s;
        if (!isfinite(s) || !isfinite(b_)){ s = 1.f; b_ = 0.f; }
        sc[tid] = s; bi[tid] = b_;
    }
    __syncthreads();
    int t = blockIdx.x * 256 + tid;
    int m = t & (MM - 1);
    int r = t >> 10; int o2 = r % 3; int b = r / 3;
    const float* hb = h1 + (size_t)b * O1 * MM + m;
    const float* w  = sw2 + o2 * O1;
    float acc = 0.f;
    #pragma unroll 8
    for (int c = 0; c < O1; c++){
        float v = hb[(size_t)c * MM] * sc[c] + bi[c];
        v = v > 0.f ? v : 0.f;
        acc += w[c] * v;
    }
    h2[t] = acc;
    float s = acc, s2 = acc * acc;
    for (int off = 32; off; off >>= 1){ s += __shfl_down(s, off); s2 += __shfl_down(s2, off); }
    __shared__ float ls[8];
    int lane = tid & 63, wid = tid >> 6;
    if (lane == 0){ ls[wid] = s; ls[4 + wid] = s2; }
    __syncthreads();
    if (tid == 0){
        atomicAdd(&stats2[2*o2],   ls[0]+ls[1]+ls[2]+ls[3]);
        atomicAdd(&stats2[2*o2+1], ls[4]+ls[5]+ls[6]+ls[7]);
    }
}

__global__ void k_fin2(const float* __restrict__ stats2, const float* __restrict__ sg2,
                       const float* __restrict__ sb2, float* __restrict__ scb2){
    int t = threadIdx.x;
    if (t < 3){
        const float invn = 1.f / (BB * MM);
        float mean = stats2[2*t] * invn;
        float var  = fmaxf(stats2[2*t+1] * invn - mean * mean, 0.f);
        float rs   = 1.f / sqrtf(var + 1e-5f);
        float s    = rs * sg2[t];
        float b    = sb2[t] - mean * s;
        if (!isfinite(s) || !isfinite(b)){ s = 1.f; b = 0.f; }
        scb2[t] = s; scb2[4 + t] = b;
    }
}

// ---------------- ball query ----------------
__global__ __launch_bounds__(256) void k_ballq(const float* __restrict__ fxyz,
                                               const float* __restrict__ h2,
                                               const float* __restrict__ scb2,
                                               const float* __restrict__ bxyz,
                                               float* __restrict__ nxyz,
                                               int* __restrict__ idxbuf){
    int q    = blockIdx.x * 4 + (threadIdx.x >> 6);
    int lane = threadIdx.x & 63;
    int b = q >> 10, m = q & (MM - 1);
    float nx[3];
    #pragma unroll
    for (int c = 0; c < 3; c++){
        float v = h2[((size_t)b * 3 + c) * MM + m] * scb2[c] + scb2[4 + c];
        v = v > 0.f ? v : 0.f;
        nx[c] = fxyz[(size_t)q * 3 + c] + v;
    }
    if (lane == 0){
        nxyz[q*3+0] = nx[0]; nxyz[q*3+1] = nx[1]; nxyz[q*3+2] = nx[2];
    }
    const float* bx = bxyz + (size_t)b * NN * 3;
    int have = 0, firstj = 0;
    int* out = idxbuf + (size_t)q * KK;
    for (int j0 = 0; j0 < NN && have < KK; j0 += 64){
        int j = j0 + lane;
        float dx = bx[j*3+0] - nx[0];
        float dy = bx[j*3+1] - nx[1];
        float dz = bx[j*3+2] - nx[2];
        float d2 = dx*dx + dy*dy + dz*dz;
        bool pred = d2 < 1.0f;
        unsigned long long mask = __ballot(pred);
        if (mask){
            if (have == 0) firstj = j0 + (__ffsll((unsigned long long)mask) - 1);
            if (pred){
                int rank = __popcll(mask & ((1ull << lane) - 1ull));
                int pos = have + rank;
                if (pos < KK) out[pos] = j;
            }
            have += (int)__popcll(mask);
        }
    }
    if (have < KK){
        int fill = (have > 0) ? firstj : 0;
        for (int p = have + lane; p < KK; p += 64) out[p] = fill;
    }
}

// ---------------- idx2 / xyzdiff ----------------
__global__ __launch_bounds__(256) void k_xyzd(const int* __restrict__ idxbuf,
                                              const float* __restrict__ bxyz,
                                              const float* __restrict__ nxyz,
                                              int* __restrict__ idx2,
                                              float4* __restrict__ xyzd){
    int l = blockIdx.x * 256 + threadIdx.x;
    int b = l >> 15;
    int q = l >> 5;
    int j = idxbuf[l];
    idx2[l] = b * NN + j;
    const float* p = bxyz + ((size_t)b * NN + j) * 3;
    xyzd[l] = make_float4(p[0] - nxyz[q*3+0], p[1] - nxyz[q*3+1], p[2] - nxyz[q*3+2], 0.f);
}

// ---------------- transpose (B,C,N) -> (B,N,C) f32, flag-aware ----------------
__global__ __launch_bounds__(256) void k_transp(const void* __restrict__ bfv,
                                                const int* __restrict__ flag,
                                                float* __restrict__ ft){
    __shared__ float tile[32][33];
    int f = *flag;
    int bid = blockIdx.x;
    int nt = bid & 511;
    int ct = (bid >> 9) & 7;
    int b  = bid >> 12;
    int tx = threadIdx.x & 31, ty = threadIdx.x >> 5;
    size_t base = ((size_t)b * CC + ct * 32) * NN + nt * 32;
    #pragma unroll
    for (int r = 0; r < 32; r += 8)
        tile[ty + r][tx] = anyf(bfv, base + (size_t)(ty + r) * NN + tx, f);
    __syncthreads();
    float* dst = ft + ((size_t)b * NN + nt * 32) * CC + ct * 32;
    #pragma unroll
    for (int r = 0; r < 32; r += 8) dst[(size_t)(ty + r) * CC + tx] = tile[tx][ty + r];
}

// ---------------- weight prep ----------------
__global__ void k_wprep(const float* __restrict__ w1, float* __restrict__ w1p,
                        float4* __restrict__ w1xp){
    int t = blockIdx.x * 256 + threadIdx.x;
    int o = t >> 8, c = t & 255;
    w1p[t] = w1[o * 259 + 3 + c];
    if (t < 512) w1xp[t] = make_float4(w1[t*259], w1[t*259+1], w1[t*259+2], 0.f);
}

// ---------------- MFMA split-bf16 GEMM ----------------
// Y[l][o] = sum_c A[o][c] * X[l][c]   (optionally X pre-transformed by BN+ReLU via scb)
// f32 accuracy via hi/lo bf16 split: a*b ~= ah*bh + ah*bl + al*bh  (error ~2^-16)
// Tile 128(o) x 128(l) x 32(c). 256 threads = 4 waves, each wave 64x64 (4x4 frags 16x16).
// LDS addresses XOR-swizzled with the col-block q (bits 5-6) so staging ds_write_b64
// groups of 16 lanes hit 32 distinct banks (was a 4-way conflict: q stride 256B).
__device__ __forceinline__ void split4(float x, float y, float z_, float w_,
                                       unsigned &h0, unsigned &h1,
                                       unsigned &lo0, unsigned &lo1){
    unsigned ux = __float_as_uint(x), uy = __float_as_uint(y);
    unsigned uz = __float_as_uint(z_), uw = __float_as_uint(w_);
    unsigned hx = ux & 0xFFFF0000u, hy = uy & 0xFFFF0000u;
    unsigned hz = uz & 0xFFFF0000u, hw = uw & 0xFFFF0000u;
    h0 = (hx >> 16) | hy;
    h1 = (hz >> 16) | hw;
    float rx = x  - __uint_as_float(hx);
    float ry = y  - __uint_as_float(hy);
    float rz = z_ - __uint_as_float(hz);
    float rw = w_ - __uint_as_float(hw);
    lo0 = (__float_as_uint(rx) >> 16) | (__float_as_uint(ry) & 0xFFFF0000u);
    lo1 = (__float_as_uint(rz) >> 16) | (__float_as_uint(rw) & 0xFFFF0000u);
}

__global__ __launch_bounds__(256) void k_gemm(const float* __restrict__ A,
                                              const float* __restrict__ X,
                                              int Cs,
                                              const float* __restrict__ scb,
                                              float* __restrict__ Y,
                                              double* __restrict__ stats){
    // LDS: fragment-linear layout [frag(8)][lane(64)][8 bf16] per buffer, q-XOR-swizzled.
    // bytes: Ahi [0,8K) Alo [8K,16K) Xhi [16K,24K) Xlo [24K,32K)
    __shared__ short lds[16384];
    char* ldsb = (char*)lds;

    const int tid  = threadIdx.x;
    const int lane = tid & 63;
    const int w    = tid >> 6;
    const int wo   = (w >> 1) * 64;
    const int wl   = (w & 1) * 64;

    // XCD-aware swizzle (gridDim.x is a multiple of 8: 2048 or 512)
    int bid = blockIdx.x;
    {
        int cpx = gridDim.x >> 3;
        bid = (bid & 7) * cpx + (bid >> 3);
    }
    const int o0 = (bid & 3) * 128;       // FF/128 == 4 o-tiles
    const int l0 = (bid >> 2) * 128;

    // staging mapping: thread t handles rows (t>>3)+32*i (i=0..3), cols q*8+h*4..+3
    const int o_loc  = tid >> 3;          // 0..31
    const int q      = (tid & 7) >> 1;    // 0..3
    const int h      = tid & 1;           // 0..1
    const int colOff = q * 8 + h * 4;
    // write byte offset within frag region: ((row&15)*16 ^ q<<5) + q*256 + h*8
    const int wbase  = ((o_loc >> 4) * 1024) + (((o_loc & 15) * 16) ^ (q << 5)) + (q << 8) + h * 8;
    // read: lane l reads 16B of frag at ((l&15)*16 ^ (l>>4)<<5) + (l>>4)*256
    const int roff   = (((lane & 15) * 16) ^ ((lane >> 4) << 5)) + ((lane >> 4) << 8);

    const float* Ap = A + (size_t)(o0 + o_loc) * Cs + colOff;
    const float* Xp = X + (size_t)(l0 + o_loc) * Cs + colOff;

    f4 acc[4][4];
    #pragma unroll
    for (int i = 0; i < 4; i++)
        #pragma unroll
        for (int j = 0; j < 4; j++)
            acc[i][j] = f4{0.f, 0.f, 0.f, 0.f};

    float4 ra[4], rx[4];
    #pragma unroll
    for (int i = 0; i < 4; i++){
        ra[i] = *(const float4*)(Ap + (size_t)(32 * i) * Cs);
        rx[i] = *(const float4*)(Xp + (size_t)(32 * i) * Cs);
    }

    for (int c0 = 0; c0 < Cs; c0 += 32){
        // convert staged regs (apply BN+ReLU to X if scb)
        unsigned ah0[4], ah1[4], aL0[4], aL1[4];
        unsigned xh0[4], xh1[4], xL0[4], xL1[4];
        float4 sc4, bi4;
        if (scb){
            sc4 = *(const float4*)(scb + c0 + colOff);
            bi4 = *(const float4*)(scb + Cs + c0 + colOff);
        }
        #pragma unroll
        for (int i = 0; i < 4; i++){
            split4(ra[i].x, ra[i].y, ra[i].z, ra[i].w, ah0[i], ah1[i], aL0[i], aL1[i]);
            float vx = rx[i].x, vy = rx[i].y, vz = rx[i].z, vw = rx[i].w;
            if (scb){
                vx = fmaxf(vx * sc4.x + bi4.x, 0.f);
                vy = fmaxf(vy * sc4.y + bi4.y, 0.f);
                vz = fmaxf(vz * sc4.z + bi4.z, 0.f);
                vw = fmaxf(vw * sc4.w + bi4.w, 0.f);
            }
            split4(vx, vy, vz, vw, xh0[i], xh1[i], xL0[i], xL1[i]);
        }
        __syncthreads();   // prev iteration's fragment reads done
        #pragma unroll
        for (int i = 0; i < 4; i++){
            int off = wbase + i * 2048;
            *(uint2*)(ldsb + off)          = make_uint2(ah0[i], ah1[i]);
            *(uint2*)(ldsb + 8192  + off)  = make_uint2(aL0[i], aL1[i]);
            *(uint2*)(ldsb + 16384 + off)  = make_uint2(xh0[i], xh1[i]);
            *(uint2*)(ldsb + 24576 + off)  = make_uint2(xL0[i], xL1[i]);
        }
        __syncthreads();
        // prefetch next K-step (latency hides under MFMA below)
        if (c0 + 32 < Cs){
            #pragma unroll
            for (int i = 0; i < 4; i++){
                ra[i] = *(const float4*)(Ap + (size_t)(32 * i) * Cs + (c0 + 32));
                rx[i] = *(const float4*)(Xp + (size_t)(32 * i) * Cs + (c0 + 32));
            }
        }
        // MFMA: 4x4 frags x 3 split terms
        b8 bhf[4], blf[4];
        #pragma unroll
        for (int ni = 0; ni < 4; ni++){
            int f = (wl >> 4) + ni;
            bhf[ni] = *(const b8*)(ldsb + 16384 + f * 1024 + roff);
            blf[ni] = *(const b8*)(ldsb + 24576 + f * 1024 + roff);
        }
        #pragma unroll
        for (int mi = 0; mi < 4; mi++){
            int f = (wo >> 4) + mi;
            b8 ahf = *(const b8*)(ldsb + f * 1024 + roff);
            b8 alf = *(const b8*)(ldsb + 8192 + f * 1024 + roff);
            #pragma unroll
            for (int ni = 0; ni < 4; ni++){
                acc[mi][ni] = __builtin_amdgcn_mfma_f32_16x16x32_bf16(ahf, bhf[ni], acc[mi][ni], 0, 0, 0);
                acc[mi][ni] = __builtin_amdgcn_mfma_f32_16x16x32_bf16(ahf, blf[ni], acc[mi][ni], 0, 0, 0);
                acc[mi][ni] = __builtin_amdgcn_mfma_f32_16x16x32_bf16(alf, bhf[ni], acc[mi][ni], 0, 0, 0);
            }
        }
    }

    // epilogue: D row (o) = 4*(lane>>4)+r, col (l) = lane&15   [m89-verified C/D layout]
    if (Y){
        #pragma unroll
        for (int mi = 0; mi < 4; mi++){
            #pragma unroll
            for (int ni = 0; ni < 4; ni++){
                int o = o0 + wo + mi * 16 + 4 * (lane >> 4);
                int l = l0 + wl + ni * 16 + (lane & 15);
                *(float4*)(Y + (size_t)l * FF + o) =
                    make_float4(acc[mi][ni][0], acc[mi][ni][1], acc[mi][ni][2], acc[mi][ni][3]);
            }
        }
    }
    if (stats){
        int slot_s = blockIdx.x & (NSLOT - 1);
        double* sp = stats + (size_t)slot_s * FF * 2;
        #pragma unroll
        for (int mi = 0; mi < 4; mi++){
            float s1[4] = {0,0,0,0}, s2[4] = {0,0,0,0};
            #pragma unroll
            for (int ni = 0; ni < 4; ni++){
                #pragma unroll
                for (int r = 0; r < 4; r++){
                    float v = acc[mi][ni][r];
                    s1[r] += v; s2[r] += v * v;
                }
            }
            #pragma unroll
            for (int off = 8; off; off >>= 1){
                #pragma unroll
                for (int r = 0; r < 4; r++){
                    s1[r] += __shfl_down(s1[r], off, 16);
                    s2[r] += __shfl_down(s2[r], off, 16);
                }
            }
            if ((lane & 15) == 0){
                int o = o0 + wo + mi * 16 + 4 * (lane >> 4);
                #pragma unroll
                for (int r = 0; r < 4; r++){
                    atomicAdd(&sp[2 * (o + r)],     (double)s1[r]);
                    atomicAdd(&sp[2 * (o + r) + 1], (double)s2[r]);
                }
            }
        }
    }
}

// ---------------- finalize BN ----------------
__global__ void k_finL(const double* __restrict__ stats, const float* __restrict__ g,
                       const float* __restrict__ bt, float* __restrict__ scb){
    int o = blockIdx.x * 256 + threadIdx.x;
    double s = 0.0, s2 = 0.0;
    for (int k = 0; k < NSLOT; k++){
        s  += stats[((size_t)k * FF + o) * 2];
        s2 += stats[((size_t)k * FF + o) * 2 + 1];
    }
    double mean = s / (double)LTOT;
    double var  = s2 / (double)LTOT - mean * mean;
    if (!(var > 0.0)) var = 0.0;
    double rs = 1.0 / sqrt(var + 1e-5);
    double sc = rs * (double)g[o];
    double bi = (double)bt[o] - mean * sc;
    float scf = (float)sc, bif = (float)bi;
    if (!isfinite(scf) || !isfinite(bif)){ scf = 1.f; bif = 0.f; }
    scb[o] = scf;
    scb[FF + o] = bif;
}

// ---------------- y1 stats ----------------
__global__ __launch_bounds__(256) void k_y1stats(const float* __restrict__ z,
                                                 const int* __restrict__ idx2,
                                                 const float4* __restrict__ xyzd,
                                                 const float4* __restrict__ w1xp,
                                                 double* __restrict__ stats){
    int tid = threadIdx.x, bid = blockIdx.x;
    int o1 = tid, o2 = tid + 256;
    float4 wa = w1xp[o1], wb = w1xp[o2];
    double s1a=0, s2a=0, s1b=0, s2b=0;
    for (int p = 0; p < LTOT/2048; p++){
        int l = bid + p * 2048;
        int r = idx2[l];
        float4 d = xyzd[l];
        const float* zr = z + (size_t)r * FF;
        float ya = zr[o1] + d.x*wa.x + d.y*wa.y + d.z*wa.z;
        float yb = zr[o2] + d.x*wb.x + d.y*wb.y + d.z*wb.z;
        s1a += ya; s2a += (double)ya*ya;
        s1b += yb; s2b += (double)yb*yb;
    }
    int slot = bid & (NSLOT - 1);
    double* sp = stats + (size_t)slot * FF * 2;
    atomicAdd(&sp[2*o1],   s1a); atomicAdd(&sp[2*o1+1], s2a);
    atomicAdd(&sp[2*o2],   s1b); atomicAdd(&sp[2*o2+1], s2b);
}

// ---------------- materialize X1 chunk ----------------
__global__ __launch_bounds__(256) void k_y1mat(const float* __restrict__ z,
                                               const int* __restrict__ idx2,
                                               const float4* __restrict__ xyzd,
                                               const float4* __restrict__ w1xp,
                                               const float* __restrict__ scb,
                                               float* __restrict__ t1, int L0){
    int tid = threadIdx.x, bid = blockIdx.x;
    int o1 = tid, o2 = tid + 256;
    float4 wa = w1xp[o1], wb = w1xp[o2];
    float sa = scb[o1], ba = scb[FF+o1], sb = scb[o2], bb = scb[FF+o2];
    for (int p = 0; p < CH/1024; p++){
        int ll = bid + p * 1024;
        int l  = L0 + ll;
        int r = idx2[l];
        float4 d = xyzd[l];
        const float* zr = z + (size_t)r * FF;
        float ya = zr[o1] + d.x*wa.x + d.y*wa.y + d.z*wa.z;
        float yb = zr[o2] + d.x*wb.x + d.y*wb.y + d.z*wb.z;
        t1[(size_t)ll * FF + o1] = fmaxf(ya * sa + ba, 0.f);
        t1[(size_t)ll * FF + o2] = fmaxf(yb * sb + bb, 0.f);
    }
}

// ---------------- final max: out[q,o] = max_k relu(bn3(y3)) — FLOAT32 OUTPUT ----------------
__global__ __launch_bounds__(256) void k_maxout(const float* __restrict__ y3,
                                                const float* __restrict__ scb,
                                                float* __restrict__ out,
                                                int q0){
    int qr = blockIdx.x;
    int q = q0 + qr;
    int o = threadIdx.x;
    const float* yb = y3 + (size_t)qr * KK * FF;
    #pragma unroll
    for (int rep = 0; rep < 2; rep++, o += 256){
        float sc = scb[o], bi = scb[FF + o];
        float mx = 0.f;
        for (int k = 0; k < KK; k++){
            float v = fmaxf(yb[(size_t)k * FF + o] * sc + bi, 0.f);
            mx = fmaxf(mx, v);
        }
        out[(size_t)q * FF + o] = mx;
    }
}

// ---------------- stage diagnostics (float sentinel, fires only on unhealthy) ----------------
__global__ __launch_bounds__(256) void k_diag(const float* __restrict__ ff,
                                              const float* __restrict__ w1f,
                                              const float* __restrict__ featT,
                                              const float* __restrict__ z,
                                              const float* __restrict__ xyzdf,
                                              const float* __restrict__ scb1,
                                              const float* __restrict__ scbL2,
                                              const float* __restrict__ scbL3,
                                              const float* __restrict__ y3,
                                              float* __restrict__ out){
    __shared__ float red[4];
    int tid = threadIdx.x;
    int bad = 0, isn = 0;
    const float* arr[9] = {ff, w1f, featT, z, xyzdf, scb1, scbL2, scbL3, y3};
    const int   len[9] = {4096, 4096, 8192, 8192, 4096, 1024, 1024, 1024, 8192};
    for (int k = 0; k < 9; k++){
        float s = 0.f;
        const float* a = arr[k];
        for (int i = tid; i < len[k]; i += 256) s += fabsf(a[i]);
        for (int off = 32; off; off >>= 1) s += __shfl_down(s, off);
        if ((tid & 63) == 0) red[tid >> 6] = s;
        __syncthreads();
        float t = red[0] + red[1] + red[2] + red[3];
        __syncthreads();
        if (bad == 0 && !(t > 1e-6f && t < 1e15f)){
            bad = k + 1;
            isn = isfinite(t) ? 0 : 1;
        }
    }
    if (tid == 0 && bad) out[0] = 512.f * bad + 256.f * isn;
}

extern "C" void kernel_launch(void* const* d_in, const int* in_sizes, int n_in,
                              void* d_out, int out_size, void* d_ws, size_t ws_size,
                              hipStream_t stream) {
    static const int NSZ[19] = {12288, 1048576, 196608, 16777216, 32768, 128, 128,
                                384, 3, 3, 132608, 512, 512, 262144, 512, 512,
                                262144, 512, 512};
    float* out = (float*)d_out;   // OUTPUT IS FLOAT32 (reference returns jnp.float32)

    char* w = (char*)d_ws;
    size_t off = 0;
    auto take = [&](size_t bytes)->size_t{
        size_t r = off; off += (bytes + 255) & ~(size_t)255; return r;
    };
    size_t o_stats1  = take(256 * 4);
    size_t o_stats2  = take(8 * 4);
    size_t o_statsA  = take((size_t)NSLOT * FF * 2 * 8);
    size_t o_statsL2 = take((size_t)NSLOT * FF * 2 * 8);
    size_t o_statsL3 = take((size_t)NSLOT * FF * 2 * 8);
    size_t zero_end  = off;
    size_t o_flags   = take(19 * 4);
    size_t o_cv[19];
    for (int i = 0; i < 19; i++){
        if (i == 3){ o_cv[i] = 0; continue; }
        o_cv[i] = take((size_t)NSZ[i] * 4);
    }
    size_t o_scb2    = take(8 * 4);
    size_t o_scb1    = take(FF * 2 * 4);
    size_t o_scbL2   = take(FF * 2 * 4);
    size_t o_scbL3   = take(FF * 2 * 4);
    size_t o_h1      = take((size_t)BB * O1 * MM * 4);
    size_t o_h2      = take((size_t)BB * 3 * MM * 4);
    size_t o_nxyz    = take((size_t)BB * MM * 3 * 4);
    size_t o_idx     = take((size_t)LTOT * 4);
    size_t o_idx2    = take((size_t)LTOT * 4);
    size_t o_xyzd    = take((size_t)LTOT * 16);
    size_t o_w1p     = take((size_t)FF * CC * 4);
    size_t o_w1xp    = take((size_t)FF * 16);
    size_t o_featT   = take((size_t)BB * NN * CC * 4);
    size_t o_t1      = o_featT;
    size_t o_t2      = o_featT + (size_t)CH * FF * 4;
    size_t o_z       = take((size_t)BB * NN * FF * 4);
    size_t small_end = off;
    // big-path extra: full t2 (all chunks) to kill 16 gemm2 + 16 y1mat recomputes
    size_t o_t2full  = take((size_t)LTOT * FF * 4);   // 268 MB
    bool big = (ws_size >= off);
    (void)n_in; (void)in_sizes; (void)out_size; (void)small_end;

    float*  stats1  = (float*) (w + o_stats1);
    float*  stats2  = (float*) (w + o_stats2);
    double* statsA  = (double*)(w + o_statsA);
    double* statsL2 = (double*)(w + o_statsL2);
    double* statsL3 = (double*)(w + o_statsL3);
    int*    flags   = (int*)   (w + o_flags);
    float*  scb2    = (float*) (w + o_scb2);
    float*  scb1    = (float*) (w + o_scb1);
    float*  scbL2   = (float*) (w + o_scbL2);
    float*  scbL3   = (float*) (w + o_scbL3);
    float*  h1      = (float*) (w + o_h1);
    float*  h2      = (float*) (w + o_h2);
    float*  nxyz    = (float*) (w + o_nxyz);
    int*    idxbuf  = (int*)   (w + o_idx);
    int*    idx2    = (int*)   (w + o_idx2);
    float4* xyzd    = (float4*)(w + o_xyzd);
    float*  w1p     = (float*) (w + o_w1p);
    float4* w1xp    = (float4*)(w + o_w1xp);
    float*  featT   = (float*) (w + o_featT);
    float*  t1      = (float*) (w + o_t1);
    float*  t2      = (float*) (w + o_t2);
    float*  z       = (float*) (w + o_z);
    float*  t2full  = (float*) (w + o_t2full);
    // big path: chunk scratch reuses featT (dead after z-GEMM)
    float*  t1c     = t1;      // == featT base, 33.5 MB
    float*  t3c     = t2;      // == featT + 33.5 MB

    hipMemsetAsync(w, 0, zero_end, stream);

    float* cv[19];
    for (int i = 0; i < 19; i++){
        k_det<<<1, 64, 0, stream>>>((const unsigned short*)d_in[i], NSZ[i], flags + i);
        if (i == 3){ cv[i] = nullptr; continue; }
        cv[i] = (float*)(w + o_cv[i]);
    }
    for (int i = 0; i < 19; i++){
        if (i == 3) continue;
        k_cvtf<<<(NSZ[i] + 255) / 256, 256, 0, stream>>>(d_in[i], cv[i], NSZ[i], flags + i);
    }
    float* fx = cv[0], *ffp = cv[1], *bx = cv[2];
    float* sw1f = cv[4], *sg1f = cv[5], *sb1f = cv[6];
    float* sw2f = cv[7], *sg2f = cv[8], *sb2f = cv[9];
    float* w1f = cv[10], *g1f = cv[11], *b1f = cv[12];
    float* w2f = cv[13], *g2f = cv[14], *b2f = cv[15];
    float* w3f = cv[16], *g3f = cv[17], *b3f = cv[18];

    k_mlp1   <<<2048, 256, 0, stream>>>(sw1f, ffp, h1, stats1);
    k_bn1mlp2<<<48,   256, 0, stream>>>(h1, stats1, sg1f, sb1f, sw2f, h2, stats2);
    k_fin2   <<<1,    64,  0, stream>>>(stats2, sg2f, sb2f, scb2);
    k_ballq  <<<BB*MM/4, 256, 0, stream>>>(fx, h2, scb2, bx, nxyz, idxbuf);
    k_xyzd   <<<LTOT/256, 256, 0, stream>>>(idxbuf, bx, nxyz, idx2, xyzd);
    k_transp <<<BB*(CC/32)*(NN/32), 256, 0, stream>>>(d_in[3], flags + 3, featT);
    k_wprep  <<<512, 256, 0, stream>>>(w1f, w1p, w1xp);

    // z = featT @ w1p^T  : (65536 x 256) x (512 x 256)^T  -> 65536 x 512
    k_gemm <<<4 * (BB*NN/128), 256, 0, stream>>>(w1p, featT, CC, nullptr, z, nullptr);

    k_y1stats<<<2048, 256, 0, stream>>>(z, idx2, xyzd, w1xp, statsA);
    k_finL  <<<2, 256, 0, stream>>>(statsA, g1f, b1f, scb1);

    const int G = 4 * (CH/128);
    if (big){
        // pass A: materialize t2full = w2 @ bn1(y1) for all chunks, accumulate L2 stats
        for (int c = 0; c < NCH2; c++){
            k_y1mat<<<1024, 256, 0, stream>>>(z, idx2, xyzd, w1xp, scb1, t1c, c*CH);
            k_gemm <<<G, 256, 0, stream>>>(w2f, t1c, FF, nullptr,
                                           t2full + (size_t)c * CH * FF, statsL2);
        }
        k_finL <<<2, 256, 0, stream>>>(statsL2, g2f, b2f, scbL2);
        // pass B: L3 stats from stored t2
        for (int c = 0; c < NCH2; c++)
            k_gemm <<<G, 256, 0, stream>>>(w3f, t2full + (size_t)c * CH * FF, FF,
                                           scbL2, nullptr, statsL3);
        k_finL <<<2, 256, 0, stream>>>(statsL3, g3f, b3f, scbL3);
        // pass C: values + maxout
        for (int c = 0; c < NCH2; c++){
            k_gemm <<<G, 256, 0, stream>>>(w3f, t2full + (size_t)c * CH * FF, FF,
                                           scbL2, t3c, nullptr);
            k_maxout<<<CH/KK, 256, 0, stream>>>(t3c, scbL3, out, c*(CH/KK));
        }
        k_diag<<<1, 256, 0, stream>>>(ffp, w1f, t1c, z, (const float*)xyzd,
                                      scb1, scbL2, scbL3, t3c, out);
    } else {
        for (int c = 0; c < NCH2; c++){
            k_y1mat<<<1024, 256, 0, stream>>>(z, idx2, xyzd, w1xp, scb1, t1, c*CH);
            k_gemm <<<G, 256, 0, stream>>>(w2f, t1, FF, nullptr, nullptr, statsL2);
        }
        k_finL <<<2, 256, 0, stream>>>(statsL2, g2f, b2f, scbL2);
        for (int c = 0; c < NCH2; c++){
            k_y1mat<<<1024, 256, 0, stream>>>(z, idx2, xyzd, w1xp, scb1, t1, c*CH);
            k_gemm <<<G, 256, 0, stream>>>(w2f, t1, FF, nullptr, t2, nullptr);
            k_gemm <<<G, 256, 0, stream>>>(w3f, t2, FF, scbL2, nullptr, statsL3);
        }
        k_finL <<<2, 256, 0, stream>>>(statsL3, g3f, b3f, scbL3);
        for (int c = 0; c < NCH2; c++){
            k_y1mat<<<1024, 256, 0, stream>>>(z, idx2, xyzd, w1xp, scb1, t1, c*CH);
            k_gemm <<<G, 256, 0, stream>>>(w2f, t1, FF, nullptr, t2, nullptr);
            k_gemm <<<G, 256, 0, stream>>>(w3f, t2, FF, scbL2, t1, nullptr);
            k_maxout<<<CH/KK, 256, 0, stream>>>(t1, scbL3, out, c*(CH/KK));
        }
        k_diag<<<1, 256, 0, stream>>>(ffp, w1f, featT, z, (const float*)xyzd,
                                      scb1, scbL2, scbL3, t1, out);
    }
}

// Round 4
// 2260.413 us; speedup vs baseline: 2.7521x; 1.1042x over previous
//
#include <hip/hip_runtime.h>
#include <hip/hip_bf16.h>
#include <hip/hip_fp16.h>

#define BB   4
#define NN   16384
#define MM   1024
#define CC   256
#define KK   32
#define O1   128
#define FF   512
#define LTOT (BB*MM*KK)   // 131072
#define NSLOT 64
#define CH   16384
#define NCH2 (LTOT/CH)    // 8

typedef float f4 __attribute__((ext_vector_type(4)));
typedef short b8 __attribute__((ext_vector_type(8)));

__device__ __forceinline__ float bf2f(unsigned short u){
    return __uint_as_float(((unsigned int)u) << 16);
}
__device__ __forceinline__ float anyf(const void* p, size_t i, int f){
    if (f == 1) return bf2f(((const unsigned short*)p)[i]);
    if (f == 2) return __half2float(((const __half*)p)[i]);
    return ((const float*)p)[i];
}

// ---- dtype detector: 0=f32, 1=bf16, 2=fp16 ----
__global__ void k_det(const unsigned short* __restrict__ u, int n, int* __restrict__ flag){
    if (threadIdx.x != 0 || blockIdx.x != 0) return;
    int W = n < 64 ? n : 64;
    bool allz = true;
    for (int k = 0; k < W; k++) if (u[k]){ allz = false; break; }
    if (allz){ *flag = 1; return; }
    if (u[0] == 0x3F80u){ *flag = 1; return; }      // bf16 1.0
    if (u[0] == 0x3C00u){ *flag = 2; return; }      // fp16 1.0
    if (W >= 2){
        unsigned int f0 = ((unsigned int)u[1] << 16) | u[0];
        if (__uint_as_float(f0) == 1.0f){ *flag = 0; return; }  // f32 1.0
    }
    int ce = 0, co = 0, ne = 0, no_ = 0;
    for (int k = 0; k < W; k++){
        unsigned short x = u[k];
        float v = fabsf(bf2f(x));
        int sane = (x == 0) || (v >= 0.0009765625f && v <= 64.f);
        if (k & 1){ no_++; co += sane; } else { ne++; ce += sane; }
    }
    if (ce * 4 >= ne * 3){ *flag = 1; return; }
    if (co * 4 >= no_ * 3 && ce * 5 < ne * 2){ *flag = 0; return; }
    *flag = 2;
}

__global__ __launch_bounds__(256) void k_cvtf(const void* __restrict__ src,
                                              float* __restrict__ dst, int n,
                                              const int* __restrict__ flag){
    int t = blockIdx.x * 256 + threadIdx.x;
    if (t >= n) return;
    dst[t] = anyf(src, t, *flag);
}

// ---------------- Stage 1 ----------------
__global__ __launch_bounds__(256) void k_mlp1(const float* __restrict__ sw1,
                                              const float* __restrict__ feat,
                                              float* __restrict__ h1,
                                              float* __restrict__ stats1){
    int t = blockIdx.x * 256 + threadIdx.x;
    int m = t & (MM - 1);
    int o = (t >> 10) & (O1 - 1);
    int b = t >> 17;
    const float* fb = feat + (size_t)b * CC * MM + m;
    const float* w  = sw1 + o * CC;
    float acc = 0.f;
    #pragma unroll 8
    for (int c = 0; c < CC; c++) acc += w[c] * fb[(size_t)c * MM];
    h1[t] = acc;
    float s = acc, s2 = acc * acc;
    for (int off = 32; off; off >>= 1){ s += __shfl_down(s, off); s2 += __shfl_down(s2, off); }
    __shared__ float ls[8];
    int lane = threadIdx.x & 63, wid = threadIdx.x >> 6;
    if (lane == 0){ ls[wid] = s; ls[4 + wid] = s2; }
    __syncthreads();
    if (threadIdx.x == 0){
        atomicAdd(&stats1[2*o],   ls[0]+ls[1]+ls[2]+ls[3]);
        atomicAdd(&stats1[2*o+1], ls[4]+ls[5]+ls[6]+ls[7]);
    }
}

// ---------------- Stage 2 ----------------
__global__ __launch_bounds__(256) void k_bn1mlp2(const float* __restrict__ h1,
                                                 const float* __restrict__ stats1,
                                                 const float* __restrict__ sg1,
                                                 const float* __restrict__ sb1,
                                                 const float* __restrict__ sw2,
                                                 float* __restrict__ h2,
                                                 float* __restrict__ stats2){
    __shared__ float sc[O1], bi[O1];
    int tid = threadIdx.x;
    if (tid < O1){
        const float invn = 1.f / (BB * MM);
        float mean = stats1[2*tid] * invn;
        float var  = fmaxf(stats1[2*tid+1] * invn - mean * mean, 0.f);
        float rs   = 1.f / sqrtf(var + 1e-5f);
        float s    = rs * sg1[tid];
        float b_   = sb1[tid] - mean * s;
        if (!isfinite(s) || !isfinite(b_)){ s = 1.f; b_ = 0.f; }
        sc[tid] = s; bi[tid] = b_;
    }
    __syncthreads();
    int t = blockIdx.x * 256 + tid;
    int m = t & (MM - 1);
    int r = t >> 10; int o2 = r % 3; int b = r / 3;
    const float* hb = h1 + (size_t)b * O1 * MM + m;
    const float* w  = sw2 + o2 * O1;
    float acc = 0.f;
    #pragma unroll 8
    for (int c = 0; c < O1; c++){
        float v = hb[(size_t)c * MM] * sc[c] + bi[c];
        v = v > 0.f ? v : 0.f;
        acc += w[c] * v;
    }
    h2[t] = acc;
    float s = acc, s2 = acc * acc;
    for (int off = 32; off; off >>= 1){ s += __shfl_down(s, off); s2 += __shfl_down(s2, off); }
    __shared__ float ls[8];
    int lane = tid & 63, wid = tid >> 6;
    if (lane == 0){ ls[wid] = s; ls[4 + wid] = s2; }
    __syncthreads();
    if (tid == 0){
        atomicAdd(&stats2[2*o2],   ls[0]+ls[1]+ls[2]+ls[3]);
        atomicAdd(&stats2[2*o2+1], ls[4]+ls[5]+ls[6]+ls[7]);
    }
}

__global__ void k_fin2(const float* __restrict__ stats2, const float* __restrict__ sg2,
                       const float* __restrict__ sb2, float* __restrict__ scb2){
    int t = threadIdx.x;
    if (t < 3){
        const float invn = 1.f / (BB * MM);
        float mean = stats2[2*t] * invn;
        float var  = fmaxf(stats2[2*t+1] * invn - mean * mean, 0.f);
        float rs   = 1.f / sqrtf(var + 1e-5f);
        float s    = rs * sg2[t];
        float b    = sb2[t] - mean * s;
        if (!isfinite(s) || !isfinite(b)){ s = 1.f; b = 0.f; }
        scb2[t] = s; scb2[4 + t] = b;
    }
}

// ---------------- ball query ----------------
__global__ __launch_bounds__(256) void k_ballq(const float* __restrict__ fxyz,
                                               const float* __restrict__ h2,
                                               const float* __restrict__ scb2,
                                               const float* __restrict__ bxyz,
                                               float* __restrict__ nxyz,
                                               int* __restrict__ idxbuf){
    int q    = blockIdx.x * 4 + (threadIdx.x >> 6);
    int lane = threadIdx.x & 63;
    int b = q >> 10, m = q & (MM - 1);
    float nx[3];
    #pragma unroll
    for (int c = 0; c < 3; c++){
        float v = h2[((size_t)b * 3 + c) * MM + m] * scb2[c] + scb2[4 + c];
        v = v > 0.f ? v : 0.f;
        nx[c] = fxyz[(size_t)q * 3 + c] + v;
    }
    if (lane == 0){
        nxyz[q*3+0] = nx[0]; nxyz[q*3+1] = nx[1]; nxyz[q*3+2] = nx[2];
    }
    const float* bx = bxyz + (size_t)b * NN * 3;
    int have = 0, firstj = 0;
    int* out = idxbuf + (size_t)q * KK;
    for (int j0 = 0; j0 < NN && have < KK; j0 += 64){
        int j = j0 + lane;
        float dx = bx[j*3+0] - nx[0];
        float dy = bx[j*3+1] - nx[1];
        float dz = bx[j*3+2] - nx[2];
        float d2 = dx*dx + dy*dy + dz*dz;
        bool pred = d2 < 1.0f;
        unsigned long long mask = __ballot(pred);
        if (mask){
            if (have == 0) firstj = j0 + (__ffsll((unsigned long long)mask) - 1);
            if (pred){
                int rank = __popcll(mask & ((1ull << lane) - 1ull));
                int pos = have + rank;
                if (pos < KK) out[pos] = j;
            }
            have += (int)__popcll(mask);
        }
    }
    if (have < KK){
        int fill = (have > 0) ? firstj : 0;
        for (int p = have + lane; p < KK; p += 64) out[p] = fill;
    }
}

// ---------------- idx2 / xyzdiff ----------------
__global__ __launch_bounds__(256) void k_xyzd(const int* __restrict__ idxbuf,
                                              const float* __restrict__ bxyz,
                                              const float* __restrict__ nxyz,
                                              int* __restrict__ idx2,
                                              float4* __restrict__ xyzd){
    int l = blockIdx.x * 256 + threadIdx.x;
    int b = l >> 15;
    int q = l >> 5;
    int j = idxbuf[l];
    idx2[l] = b * NN + j;
    const float* p = bxyz + ((size_t)b * NN + j) * 3;
    xyzd[l] = make_float4(p[0] - nxyz[q*3+0], p[1] - nxyz[q*3+1], p[2] - nxyz[q*3+2], 0.f);
}

// ---------------- transpose (B,C,N) -> (B,N,C) f32, flag-aware ----------------
__global__ __launch_bounds__(256) void k_transp(const void* __restrict__ bfv,
                                                const int* __restrict__ flag,
                                                float* __restrict__ ft){
    __shared__ float tile[32][33];
    int f = *flag;
    int bid = blockIdx.x;
    int nt = bid & 511;
    int ct = (bid >> 9) & 7;
    int b  = bid >> 12;
    int tx = threadIdx.x & 31, ty = threadIdx.x >> 5;
    size_t base = ((size_t)b * CC + ct * 32) * NN + nt * 32;
    #pragma unroll
    for (int r = 0; r < 32; r += 8)
        tile[ty + r][tx] = anyf(bfv, base + (size_t)(ty + r) * NN + tx, f);
    __syncthreads();
    float* dst = ft + ((size_t)b * NN + nt * 32) * CC + ct * 32;
    #pragma unroll
    for (int r = 0; r < 32; r += 8) dst[(size_t)(ty + r) * CC + tx] = tile[tx][ty + r];
}

// ---------------- weight prep: w1 -> bf16 hi/lo planes + xyz part ----------------
__global__ void k_wprep(const float* __restrict__ w1,
                        unsigned short* __restrict__ w1h,
                        unsigned short* __restrict__ w1l,
                        float4* __restrict__ w1xp){
    int t = blockIdx.x * 256 + threadIdx.x;
    int o = t >> 8, c = t & 255;
    float f = w1[o * 259 + 3 + c];
    unsigned u = __float_as_uint(f);
    unsigned hh = u & 0xFFFF0000u;
    w1h[t] = (unsigned short)(hh >> 16);
    float f2 = f - __uint_as_float(hh);
    w1l[t] = (unsigned short)(__float_as_uint(f2) >> 16);
    if (t < 512) w1xp[t] = make_float4(w1[t*259], w1[t*259+1], w1[t*259+2], 0.f);
}

// ---------------- generic f32 -> bf16 hi/lo split ----------------
__global__ __launch_bounds__(256) void k_wsplit(const float* __restrict__ src,
                                                unsigned short* __restrict__ h,
                                                unsigned short* __restrict__ l, int n){
    int t = blockIdx.x * 256 + threadIdx.x;
    if (t >= n) return;
    float f = src[t];
    unsigned u = __float_as_uint(f);
    unsigned hh = u & 0xFFFF0000u;
    h[t] = (unsigned short)(hh >> 16);
    float f2 = f - __uint_as_float(hh);
    l[t] = (unsigned short)(__float_as_uint(f2) >> 16);
}

// ---------------- MFMA split-bf16 GEMM, templated ----------------
// Y[l][o] = sum_c A[o][c] * X'[l][c]
//   XM=0: X' = X (row-major [l][Cs]), optionally BN+ReLU via scb
//   XM=1: X'[l][c] = relu(bn1(z[idx2[Lbase+l]][c] + xyzd[Lbase+l]·w1xp[c]))  (scb = BN1)
//   OM=0: write Y (if non-null) f32; accumulate stats (if non-null)
//   OM=1: fused maxout: out[q][o] = max_k relu(scbO[o]*v + scbO[FF+o]) over k=0..31
// A is pre-split into bf16 hi/lo planes (Ah/Al). Accuracy: ah*bh+ah*bl+al*bh (~2^-16).
// Tile 128(o) x 128(l) x 32(c), 4 waves, LDS q-XOR swizzled (conflict-free, round-3).
__device__ __forceinline__ void split4(float x, float y, float z_, float w_,
                                       unsigned &h0, unsigned &h1,
                                       unsigned &lo0, unsigned &lo1){
    unsigned ux = __float_as_uint(x), uy = __float_as_uint(y);
    unsigned uz = __float_as_uint(z_), uw = __float_as_uint(w_);
    unsigned hx = ux & 0xFFFF0000u, hy = uy & 0xFFFF0000u;
    unsigned hz = uz & 0xFFFF0000u, hw = uw & 0xFFFF0000u;
    h0 = (hx >> 16) | hy;
    h1 = (hz >> 16) | hw;
    float rx = x  - __uint_as_float(hx);
    float ry = y  - __uint_as_float(hy);
    float rz = z_ - __uint_as_float(hz);
    float rw = w_ - __uint_as_float(hw);
    lo0 = (__float_as_uint(rx) >> 16) | (__float_as_uint(ry) & 0xFFFF0000u);
    lo1 = (__float_as_uint(rz) >> 16) | (__float_as_uint(rw) & 0xFFFF0000u);
}

template<int XM, int OM>
__global__ __launch_bounds__(256) void k_gemm(const unsigned short* __restrict__ Ah,
                                              const unsigned short* __restrict__ Al,
                                              const float* __restrict__ X,
                                              int Cs,
                                              const float* __restrict__ scb,
                                              const int* __restrict__ idx2,
                                              const float4* __restrict__ xyzd,
                                              const float4* __restrict__ w1xp,
                                              int Lbase,
                                              float* __restrict__ Y,
                                              const float* __restrict__ scbO,
                                              float* __restrict__ outp,
                                              double* __restrict__ stats){
    __shared__ short lds[16384];
    char* ldsb = (char*)lds;

    const int tid  = threadIdx.x;
    const int lane = tid & 63;
    const int w    = tid >> 6;
    const int wo   = (w >> 1) * 64;
    const int wl   = (w & 1) * 64;

    int bid = blockIdx.x;
    {
        int cpx = gridDim.x >> 3;             // grid % 8 == 0 always
        bid = (bid & 7) * cpx + (bid >> 3);
    }
    const int o0 = (bid & 3) * 128;
    const int l0 = (bid >> 2) * 128;

    const int o_loc  = tid >> 3;          // 0..31 (row handled, +32*i)
    const int q      = (tid & 7) >> 1;    // col block
    const int h      = tid & 1;
    const int colOff = q * 8 + h * 4;
    const int wbase  = ((o_loc >> 4) * 1024) + (((o_loc & 15) * 16) ^ (q << 5)) + (q << 8) + h * 8;
    const int roff   = (((lane & 15) * 16) ^ ((lane >> 4) << 5)) + ((lane >> 4) << 8);

    const unsigned short* Ahp = Ah + (size_t)(o0 + o_loc) * Cs + colOff;
    const unsigned short* Alp = Al + (size_t)(o0 + o_loc) * Cs + colOff;

    // X row descriptors
    int   rI[4];
    float ddx[4], ddy[4], ddz[4];
    const float* Xp = nullptr;
    if (XM == 1){
        #pragma unroll
        for (int i = 0; i < 4; i++){
            int lg = Lbase + l0 + o_loc + 32 * i;
            rI[i] = idx2[lg];
            float4 dd = xyzd[lg];
            ddx[i] = dd.x; ddy[i] = dd.y; ddz[i] = dd.z;
        }
    } else {
        Xp = X + (size_t)(l0 + o_loc) * Cs + colOff;
    }

    f4 acc[4][4];
    #pragma unroll
    for (int i = 0; i < 4; i++)
        #pragma unroll
        for (int j = 0; j < 4; j++)
            acc[i][j] = f4{0.f, 0.f, 0.f, 0.f};

    uint2  rah[4], ral[4];
    float4 rx[4];
    #pragma unroll
    for (int i = 0; i < 4; i++){
        rah[i] = *(const uint2*)(Ahp + (size_t)(32 * i) * Cs);
        ral[i] = *(const uint2*)(Alp + (size_t)(32 * i) * Cs);
        if (XM == 1) rx[i] = *(const float4*)(X + (size_t)rI[i] * FF + colOff);
        else         rx[i] = *(const float4*)(Xp + (size_t)(32 * i) * Cs);
    }

    for (int c0 = 0; c0 < Cs; c0 += 32){
        unsigned xh0[4], xh1[4], xL0[4], xL1[4];
        float4 sc4, bi4;
        if (scb){
            sc4 = *(const float4*)(scb + c0 + colOff);
            bi4 = *(const float4*)(scb + Cs + c0 + colOff);
        }
        float4 wv0, wv1, wv2, wv3;
        if (XM == 1){
            wv0 = w1xp[c0 + colOff + 0];
            wv1 = w1xp[c0 + colOff + 1];
            wv2 = w1xp[c0 + colOff + 2];
            wv3 = w1xp[c0 + colOff + 3];
        }
        #pragma unroll
        for (int i = 0; i < 4; i++){
            float vx = rx[i].x, vy = rx[i].y, vz = rx[i].z, vw = rx[i].w;
            if (XM == 1){
                vx += ddx[i]*wv0.x + ddy[i]*wv0.y + ddz[i]*wv0.z;
                vy += ddx[i]*wv1.x + ddy[i]*wv1.y + ddz[i]*wv1.z;
                vz += ddx[i]*wv2.x + ddy[i]*wv2.y + ddz[i]*wv2.z;
                vw += ddx[i]*wv3.x + ddy[i]*wv3.y + ddz[i]*wv3.z;
            }
            if (scb){
                vx = fmaxf(vx * sc4.x + bi4.x, 0.f);
                vy = fmaxf(vy * sc4.y + bi4.y, 0.f);
                vz = fmaxf(vz * sc4.z + bi4.z, 0.f);
                vw = fmaxf(vw * sc4.w + bi4.w, 0.f);
            }
            split4(vx, vy, vz, vw, xh0[i], xh1[i], xL0[i], xL1[i]);
        }
        __syncthreads();   // prev iteration's fragment reads done
        #pragma unroll
        for (int i = 0; i < 4; i++){
            int off = wbase + i * 2048;
            *(uint2*)(ldsb + off)          = rah[i];
            *(uint2*)(ldsb + 8192  + off)  = ral[i];
            *(uint2*)(ldsb + 16384 + off)  = make_uint2(xh0[i], xh1[i]);
            *(uint2*)(ldsb + 24576 + off)  = make_uint2(xL0[i], xL1[i]);
        }
        __syncthreads();
        if (c0 + 32 < Cs){
            #pragma unroll
            for (int i = 0; i < 4; i++){
                rah[i] = *(const uint2*)(Ahp + (size_t)(32 * i) * Cs + (c0 + 32));
                ral[i] = *(const uint2*)(Alp + (size_t)(32 * i) * Cs + (c0 + 32));
                if (XM == 1) rx[i] = *(const float4*)(X + (size_t)rI[i] * FF + colOff + (c0 + 32));
                else         rx[i] = *(const float4*)(Xp + (size_t)(32 * i) * Cs + (c0 + 32));
            }
        }
        b8 bhf[4], blf[4];
        #pragma unroll
        for (int ni = 0; ni < 4; ni++){
            int f = (wl >> 4) + ni;
            bhf[ni] = *(const b8*)(ldsb + 16384 + f * 1024 + roff);
            blf[ni] = *(const b8*)(ldsb + 24576 + f * 1024 + roff);
        }
        #pragma unroll
        for (int mi = 0; mi < 4; mi++){
            int f = (wo >> 4) + mi;
            b8 ahf = *(const b8*)(ldsb + f * 1024 + roff);
            b8 alf = *(const b8*)(ldsb + 8192 + f * 1024 + roff);
            #pragma unroll
            for (int ni = 0; ni < 4; ni++){
                acc[mi][ni] = __builtin_amdgcn_mfma_f32_16x16x32_bf16(ahf, bhf[ni], acc[mi][ni], 0, 0, 0);
                acc[mi][ni] = __builtin_amdgcn_mfma_f32_16x16x32_bf16(ahf, blf[ni], acc[mi][ni], 0, 0, 0);
                acc[mi][ni] = __builtin_amdgcn_mfma_f32_16x16x32_bf16(alf, bhf[ni], acc[mi][ni], 0, 0, 0);
            }
        }
    }

    // D layout: o = wo + mi*16 + 4*(lane>>4) + r,  l = wl + ni*16 + (lane&15)
    if (OM == 0){
        if (Y){
            #pragma unroll
            for (int mi = 0; mi < 4; mi++){
                #pragma unroll
                for (int ni = 0; ni < 4; ni++){
                    int o = o0 + wo + mi * 16 + 4 * (lane >> 4);
                    int l = l0 + wl + ni * 16 + (lane & 15);
                    *(float4*)(Y + (size_t)l * FF + o) =
                        make_float4(acc[mi][ni][0], acc[mi][ni][1], acc[mi][ni][2], acc[mi][ni][3]);
                }
            }
        }
        if (stats){
            int slot_s = blockIdx.x & (NSLOT - 1);
            double* sp = stats + (size_t)slot_s * FF * 2;
            #pragma unroll
            for (int mi = 0; mi < 4; mi++){
                float s1[4] = {0,0,0,0}, s2[4] = {0,0,0,0};
                #pragma unroll
                for (int ni = 0; ni < 4; ni++){
                    #pragma unroll
                    for (int r = 0; r < 4; r++){
                        float v = acc[mi][ni][r];
                        s1[r] += v; s2[r] += v * v;
                    }
                }
                #pragma unroll
                for (int off = 8; off; off >>= 1){
                    #pragma unroll
                    for (int r = 0; r < 4; r++){
                        s1[r] += __shfl_down(s1[r], off, 16);
                        s2[r] += __shfl_down(s2[r], off, 16);
                    }
                }
                if ((lane & 15) == 0){
                    int o = o0 + wo + mi * 16 + 4 * (lane >> 4);
                    #pragma unroll
                    for (int r = 0; r < 4; r++){
                        atomicAdd(&sp[2 * (o + r)],     (double)s1[r]);
                        atomicAdd(&sp[2 * (o + r) + 1], (double)s2[r]);
                    }
                }
            }
        }
    } else {
        // fused maxout: q-group g covers l = wl + g*32 + [0,32) == ni in {2g,2g+1} x (lane&15)
        #pragma unroll
        for (int mi = 0; mi < 4; mi++){
            #pragma unroll
            for (int g = 0; g < 2; g++){
                float vmx[4], vmn[4];
                #pragma unroll
                for (int r = 0; r < 4; r++){
                    float a0 = acc[mi][2*g][r], a1 = acc[mi][2*g+1][r];
                    vmx[r] = fmaxf(a0, a1); vmn[r] = fminf(a0, a1);
                }
                #pragma unroll
                for (int off = 8; off; off >>= 1){
                    #pragma unroll
                    for (int r = 0; r < 4; r++){
                        vmx[r] = fmaxf(vmx[r], __shfl_down(vmx[r], off, 16));
                        vmn[r] = fminf(vmn[r], __shfl_down(vmn[r], off, 16));
                    }
                }
                if ((lane & 15) == 0){
                    int qg = (Lbase + l0 + wl) / 32 + g;
                    #pragma unroll
                    for (int r = 0; r < 4; r++){
                        int o = o0 + wo + mi * 16 + 4 * (lane >> 4) + r;
                        float sc = scbO[o], bi = scbO[FF + o];
                        float v = sc >= 0.f ? vmx[r] : vmn[r];
                        outp[(size_t)qg * FF + o] = fmaxf(sc * v + bi, 0.f);
                    }
                }
            }
        }
    }
}

// ---------------- finalize BN ----------------
__global__ void k_finL(const double* __restrict__ stats, const float* __restrict__ g,
                       const float* __restrict__ bt, float* __restrict__ scb){
    int o = blockIdx.x * 256 + threadIdx.x;
    double s = 0.0, s2 = 0.0;
    for (int k = 0; k < NSLOT; k++){
        s  += stats[((size_t)k * FF + o) * 2];
        s2 += stats[((size_t)k * FF + o) * 2 + 1];
    }
    double mean = s / (double)LTOT;
    double var  = s2 / (double)LTOT - mean * mean;
    if (!(var > 0.0)) var = 0.0;
    double rs = 1.0 / sqrt(var + 1e-5);
    double sc = rs * (double)g[o];
    double bi = (double)bt[o] - mean * sc;
    float scf = (float)sc, bif = (float)bi;
    if (!isfinite(scf) || !isfinite(bif)){ scf = 1.f; bif = 0.f; }
    scb[o] = scf;
    scb[FF + o] = bif;
}

// ---------------- y1 stats ----------------
__global__ __launch_bounds__(256) void k_y1stats(const float* __restrict__ z,
                                                 const int* __restrict__ idx2,
                                                 const float4* __restrict__ xyzd,
                                                 const float4* __restrict__ w1xp,
                                                 double* __restrict__ stats){
    int tid = threadIdx.x, bid = blockIdx.x;
    int o1 = tid, o2 = tid + 256;
    float4 wa = w1xp[o1], wb = w1xp[o2];
    double s1a=0, s2a=0, s1b=0, s2b=0;
    for (int p = 0; p < LTOT/2048; p++){
        int l = bid + p * 2048;
        int r = idx2[l];
        float4 d = xyzd[l];
        const float* zr = z + (size_t)r * FF;
        float ya = zr[o1] + d.x*wa.x + d.y*wa.y + d.z*wa.z;
        float yb = zr[o2] + d.x*wb.x + d.y*wb.y + d.z*wb.z;
        s1a += ya; s2a += (double)ya*ya;
        s1b += yb; s2b += (double)yb*yb;
    }
    int slot = bid & (NSLOT - 1);
    double* sp = stats + (size_t)slot * FF * 2;
    atomicAdd(&sp[2*o1],   s1a); atomicAdd(&sp[2*o1+1], s2a);
    atomicAdd(&sp[2*o2],   s1b); atomicAdd(&sp[2*o2+1], s2b);
}

// ---------------- stage diagnostics (float sentinel, fires only on unhealthy) ----------------
__global__ __launch_bounds__(256) void k_diag(const float* __restrict__ ff,
                                              const float* __restrict__ w1f,
                                              const float* __restrict__ featT,
                                              const float* __restrict__ z,
                                              const float* __restrict__ xyzdf,
                                              const float* __restrict__ scb1,
                                              const float* __restrict__ scbL2,
                                              const float* __restrict__ scbL3,
                                              const float* __restrict__ y3,
                                              float* __restrict__ out){
    __shared__ float red[4];
    int tid = threadIdx.x;
    int bad = 0, isn = 0;
    const float* arr[9] = {ff, w1f, featT, z, xyzdf, scb1, scbL2, scbL3, y3};
    const int   len[9] = {4096, 4096, 8192, 8192, 4096, 1024, 1024, 1024, 8192};
    for (int k = 0; k < 9; k++){
        float s = 0.f;
        const float* a = arr[k];
        for (int i = tid; i < len[k]; i += 256) s += fabsf(a[i]);
        for (int off = 32; off; off >>= 1) s += __shfl_down(s, off);
        if ((tid & 63) == 0) red[tid >> 6] = s;
        __syncthreads();
        float t = red[0] + red[1] + red[2] + red[3];
        __syncthreads();
        if (bad == 0 && !(t > 1e-6f && t < 1e15f)){
            bad = k + 1;
            isn = isfinite(t) ? 0 : 1;
        }
    }
    if (tid == 0 && bad) out[0] = 512.f * bad + 256.f * isn;
}

extern "C" void kernel_launch(void* const* d_in, const int* in_sizes, int n_in,
                              void* d_out, int out_size, void* d_ws, size_t ws_size,
                              hipStream_t stream) {
    static const int NSZ[19] = {12288, 1048576, 196608, 16777216, 32768, 128, 128,
                                384, 3, 3, 132608, 512, 512, 262144, 512, 512,
                                262144, 512, 512};
    float* out = (float*)d_out;   // OUTPUT IS FLOAT32

    char* w = (char*)d_ws;
    size_t off = 0;
    auto take = [&](size_t bytes)->size_t{
        size_t r = off; off += (bytes + 255) & ~(size_t)255; return r;
    };
    size_t o_stats1  = take(256 * 4);
    size_t o_stats2  = take(8 * 4);
    size_t o_statsA  = take((size_t)NSLOT * FF * 2 * 8);
    size_t o_statsL2 = take((size_t)NSLOT * FF * 2 * 8);
    size_t o_statsL3 = take((size_t)NSLOT * FF * 2 * 8);
    size_t zero_end  = off;
    size_t o_flags   = take(19 * 4);
    size_t o_cv[19];
    for (int i = 0; i < 19; i++){
        if (i == 3){ o_cv[i] = 0; continue; }
        o_cv[i] = take((size_t)NSZ[i] * 4);
    }
    size_t o_scb2    = take(8 * 4);
    size_t o_scb1    = take(FF * 2 * 4);
    size_t o_scbL2   = take(FF * 2 * 4);
    size_t o_scbL3   = take(FF * 2 * 4);
    size_t o_h1      = take((size_t)BB * O1 * MM * 4);
    size_t o_h2      = take((size_t)BB * 3 * MM * 4);
    size_t o_nxyz    = take((size_t)BB * MM * 3 * 4);
    size_t o_idx     = take((size_t)LTOT * 4);
    size_t o_idx2    = take((size_t)LTOT * 4);
    size_t o_xyzd    = take((size_t)LTOT * 16);
    size_t o_w1h     = take((size_t)FF * CC * 2);
    size_t o_w1l     = take((size_t)FF * CC * 2);
    size_t o_w2h     = take((size_t)FF * FF * 2);
    size_t o_w2l     = take((size_t)FF * FF * 2);
    size_t o_w3h     = take((size_t)FF * FF * 2);
    size_t o_w3l     = take((size_t)FF * FF * 2);
    size_t o_w1xp    = take((size_t)FF * 16);
    size_t o_z       = take((size_t)BB * NN * FF * 4);    // 134 MB (before featT!)
    size_t o_featT   = take((size_t)BB * NN * CC * 4);    // 67 MB, dead after z-GEMM
    // big path: t2full (268 MB) overlays featT and extends beyond
    size_t o_t2full  = o_featT;
    size_t big_end   = o_featT + (size_t)LTOT * FF * 4;
    bool   big       = (ws_size >= big_end) && (big_end > o_featT);
    (void)n_in; (void)in_sizes; (void)out_size;

    float*  stats1  = (float*) (w + o_stats1);
    float*  stats2  = (float*) (w + o_stats2);
    double* statsA  = (double*)(w + o_statsA);
    double* statsL2 = (double*)(w + o_statsL2);
    double* statsL3 = (double*)(w + o_statsL3);
    int*    flags   = (int*)   (w + o_flags);
    float*  scb2    = (float*) (w + o_scb2);
    float*  scb1    = (float*) (w + o_scb1);
    float*  scbL2   = (float*) (w + o_scbL2);
    float*  scbL3   = (float*) (w + o_scbL3);
    float*  h1      = (float*) (w + o_h1);
    float*  h2      = (float*) (w + o_h2);
    float*  nxyz    = (float*) (w + o_nxyz);
    int*    idxbuf  = (int*)   (w + o_idx);
    int*    idx2    = (int*)   (w + o_idx2);
    float4* xyzd    = (float4*)(w + o_xyzd);
    unsigned short* w1h = (unsigned short*)(w + o_w1h);
    unsigned short* w1l = (unsigned short*)(w + o_w1l);
    unsigned short* w2h = (unsigned short*)(w + o_w2h);
    unsigned short* w2l = (unsigned short*)(w + o_w2l);
    unsigned short* w3h = (unsigned short*)(w + o_w3h);
    unsigned short* w3l = (unsigned short*)(w + o_w3l);
    float4* w1xp    = (float4*)(w + o_w1xp);
    float*  featT   = (float*) (w + o_featT);
    float*  z       = (float*) (w + o_z);
    float*  t2full  = (float*) (w + o_t2full);
    float*  t2c     = (float*) (w + o_featT);   // 33.5 MB chunk scratch (featT dead)

    hipMemsetAsync(w, 0, zero_end, stream);

    float* cv[19];
    for (int i = 0; i < 19; i++){
        k_det<<<1, 64, 0, stream>>>((const unsigned short*)d_in[i], NSZ[i], flags + i);
        if (i == 3){ cv[i] = nullptr; continue; }
        cv[i] = (float*)(w + o_cv[i]);
    }
    for (int i = 0; i < 19; i++){
        if (i == 3) continue;
        k_cvtf<<<(NSZ[i] + 255) / 256, 256, 0, stream>>>(d_in[i], cv[i], NSZ[i], flags + i);
    }
    float* fx = cv[0], *ffp = cv[1], *bx = cv[2];
    float* sw1f = cv[4], *sg1f = cv[5], *sb1f = cv[6];
    float* sw2f = cv[7], *sg2f = cv[8], *sb2f = cv[9];
    float* w1f = cv[10], *g1f = cv[11], *b1f = cv[12];
    float* w2f = cv[13], *g2f = cv[14], *b2f = cv[15];
    float* w3f = cv[16], *g3f = cv[17], *b3f = cv[18];

    k_mlp1   <<<2048, 256, 0, stream>>>(sw1f, ffp, h1, stats1);
    k_bn1mlp2<<<48,   256, 0, stream>>>(h1, stats1, sg1f, sb1f, sw2f, h2, stats2);
    k_fin2   <<<1,    64,  0, stream>>>(stats2, sg2f, sb2f, scb2);
    k_ballq  <<<BB*MM/4, 256, 0, stream>>>(fx, h2, scb2, bx, nxyz, idxbuf);
    k_xyzd   <<<LTOT/256, 256, 0, stream>>>(idxbuf, bx, nxyz, idx2, xyzd);
    k_transp <<<BB*(CC/32)*(NN/32), 256, 0, stream>>>(d_in[3], flags + 3, featT);
    k_wprep  <<<512, 256, 0, stream>>>(w1f, w1h, w1l, w1xp);
    k_wsplit <<<1024, 256, 0, stream>>>(w2f, w2h, w2l, FF*FF);
    k_wsplit <<<1024, 256, 0, stream>>>(w3f, w3h, w3l, FF*FF);

    // z = featT @ w1^T : (65536 x 256) x (512 x 256)^T -> 65536 x 512
    k_gemm<0,0><<<4 * (BB*NN/128), 256, 0, stream>>>(w1h, w1l, featT, CC, nullptr,
            nullptr, nullptr, nullptr, 0, z, nullptr, nullptr, nullptr);

    k_y1stats<<<2048, 256, 0, stream>>>(z, idx2, xyzd, w1xp, statsA);
    k_finL  <<<2, 256, 0, stream>>>(statsA, g1f, b1f, scb1);

    const int GFULL = 4 * (LTOT/128);   // 4096
    const int GCH   = 4 * (CH/128);     // 512
    if (big){
        // pass A: t2full = w2 @ relu(bn1(y1)) (y1 fused), + L2 stats — one dispatch
        k_gemm<1,0><<<GFULL, 256, 0, stream>>>(w2h, w2l, z, FF, scb1,
                idx2, xyzd, w1xp, 0, t2full, nullptr, nullptr, statsL2);
        k_finL <<<2, 256, 0, stream>>>(statsL2, g2f, b2f, scbL2);
        // pass B: L3 stats from stored t2
        k_gemm<0,0><<<GFULL, 256, 0, stream>>>(w3h, w3l, t2full, FF, scbL2,
                nullptr, nullptr, nullptr, 0, nullptr, nullptr, nullptr, statsL3);
        k_finL <<<2, 256, 0, stream>>>(statsL3, g3f, b3f, scbL3);
        // pass C: values + fused maxout
        k_gemm<0,1><<<GFULL, 256, 0, stream>>>(w3h, w3l, t2full, FF, scbL2,
                nullptr, nullptr, nullptr, 0, nullptr, scbL3, out, nullptr);
        k_diag<<<1, 256, 0, stream>>>(ffp, w1f, t2full, z, (const float*)xyzd,
                                      scb1, scbL2, scbL3, t2full, out);
    } else {
        // pass 1: L2 stats only (no Y storage needed!) — one dispatch
        k_gemm<1,0><<<GFULL, 256, 0, stream>>>(w2h, w2l, z, FF, scb1,
                idx2, xyzd, w1xp, 0, nullptr, nullptr, nullptr, statsL2);
        k_finL <<<2, 256, 0, stream>>>(statsL2, g2f, b2f, scbL2);
        // pass 2: per chunk: recompute t2, accumulate L3 stats
        for (int c = 0; c < NCH2; c++){
            k_gemm<1,0><<<GCH, 256, 0, stream>>>(w2h, w2l, z, FF, scb1,
                    idx2, xyzd, w1xp, c*CH, t2c, nullptr, nullptr, nullptr);
            k_gemm<0,0><<<GCH, 256, 0, stream>>>(w3h, w3l, t2c, FF, scbL2,
                    nullptr, nullptr, nullptr, 0, nullptr, nullptr, nullptr, statsL3);
        }
        k_finL <<<2, 256, 0, stream>>>(statsL3, g3f, b3f, scbL3);
        // pass 3: per chunk: recompute t2, gemm3 + fused maxout
        for (int c = 0; c < NCH2; c++){
            k_gemm<1,0><<<GCH, 256, 0, stream>>>(w2h, w2l, z, FF, scb1,
                    idx2, xyzd, w1xp, c*CH, t2c, nullptr, nullptr, nullptr);
            k_gemm<0,1><<<GCH, 256, 0, stream>>>(w3h, w3l, t2c, FF, scbL2,
                    nullptr, nullptr, nullptr, c*CH, nullptr, scbL3, out, nullptr);
        }
        k_diag<<<1, 256, 0, stream>>>(ffp, w1f, t2c, z, (const float*)xyzd,
                                      scb1, scbL2, scbL3, t2c, out);
    }
}

// Round 5
// 1677.023 us; speedup vs baseline: 3.7095x; 1.3479x over previous
//
#include <hip/hip_runtime.h>
#include <hip/hip_bf16.h>
#include <hip/hip_fp16.h>

#define BB   4
#define NN   16384
#define MM   1024
#define CC   256
#define KK   32
#define O1   128
#define FF   512
#define LTOT (BB*MM*KK)   // 131072
#define NSLOT 64
#define CH   16384
#define NCH2 (LTOT/CH)    // 8

typedef float f4 __attribute__((ext_vector_type(4)));
typedef short b8 __attribute__((ext_vector_type(8)));

__device__ __forceinline__ float bf2f(unsigned short u){
    return __uint_as_float(((unsigned int)u) << 16);
}
__device__ __forceinline__ float anyf(const void* p, size_t i, int f){
    if (f == 1) return bf2f(((const unsigned short*)p)[i]);
    if (f == 2) return __half2float(((const __half*)p)[i]);
    return ((const float*)p)[i];
}

// ---- dtype detector: 0=f32, 1=bf16, 2=fp16 ----
__global__ void k_det(const unsigned short* __restrict__ u, int n, int* __restrict__ flag){
    if (threadIdx.x != 0 || blockIdx.x != 0) return;
    int W = n < 64 ? n : 64;
    bool allz = true;
    for (int k = 0; k < W; k++) if (u[k]){ allz = false; break; }
    if (allz){ *flag = 1; return; }
    if (u[0] == 0x3F80u){ *flag = 1; return; }      // bf16 1.0
    if (u[0] == 0x3C00u){ *flag = 2; return; }      // fp16 1.0
    if (W >= 2){
        unsigned int f0 = ((unsigned int)u[1] << 16) | u[0];
        if (__uint_as_float(f0) == 1.0f){ *flag = 0; return; }  // f32 1.0
    }
    int ce = 0, co = 0, ne = 0, no_ = 0;
    for (int k = 0; k < W; k++){
        unsigned short x = u[k];
        float v = fabsf(bf2f(x));
        int sane = (x == 0) || (v >= 0.0009765625f && v <= 64.f);
        if (k & 1){ no_++; co += sane; } else { ne++; ce += sane; }
    }
    if (ce * 4 >= ne * 3){ *flag = 1; return; }
    if (co * 4 >= no_ * 3 && ce * 5 < ne * 2){ *flag = 0; return; }
    *flag = 2;
}

__global__ __launch_bounds__(256) void k_cvtf(const void* __restrict__ src,
                                              float* __restrict__ dst, int n,
                                              const int* __restrict__ flag){
    int t = blockIdx.x * 256 + threadIdx.x;
    if (t >= n) return;
    dst[t] = anyf(src, t, *flag);
}

// ---------------- Stage 1 ----------------
__global__ __launch_bounds__(256) void k_mlp1(const float* __restrict__ sw1,
                                              const float* __restrict__ feat,
                                              float* __restrict__ h1,
                                              float* __restrict__ stats1){
    int t = blockIdx.x * 256 + threadIdx.x;
    int m = t & (MM - 1);
    int o = (t >> 10) & (O1 - 1);
    int b = t >> 17;
    const float* fb = feat + (size_t)b * CC * MM + m;
    const float* w  = sw1 + o * CC;
    float acc = 0.f;
    #pragma unroll 8
    for (int c = 0; c < CC; c++) acc += w[c] * fb[(size_t)c * MM];
    h1[t] = acc;
    float s = acc, s2 = acc * acc;
    for (int off = 32; off; off >>= 1){ s += __shfl_down(s, off); s2 += __shfl_down(s2, off); }
    __shared__ float ls[8];
    int lane = threadIdx.x & 63, wid = threadIdx.x >> 6;
    if (lane == 0){ ls[wid] = s; ls[4 + wid] = s2; }
    __syncthreads();
    if (threadIdx.x == 0){
        atomicAdd(&stats1[2*o],   ls[0]+ls[1]+ls[2]+ls[3]);
        atomicAdd(&stats1[2*o+1], ls[4]+ls[5]+ls[6]+ls[7]);
    }
}

// ---------------- Stage 2 ----------------
__global__ __launch_bounds__(256) void k_bn1mlp2(const float* __restrict__ h1,
                                                 const float* __restrict__ stats1,
                                                 const float* __restrict__ sg1,
                                                 const float* __restrict__ sb1,
                                                 const float* __restrict__ sw2,
                                                 float* __restrict__ h2,
                                                 float* __restrict__ stats2){
    __shared__ float sc[O1], bi[O1];
    int tid = threadIdx.x;
    if (tid < O1){
        const float invn = 1.f / (BB * MM);
        float mean = stats1[2*tid] * invn;
        float var  = fmaxf(stats1[2*tid+1] * invn - mean * mean, 0.f);
        float rs   = 1.f / sqrtf(var + 1e-5f);
        float s    = rs * sg1[tid];
        float b_   = sb1[tid] - mean * s;
        if (!isfinite(s) || !isfinite(b_)){ s = 1.f; b_ = 0.f; }
        sc[tid] = s; bi[tid] = b_;
    }
    __syncthreads();
    int t = blockIdx.x * 256 + tid;
    int m = t & (MM - 1);
    int r = t >> 10; int o2 = r % 3; int b = r / 3;
    const float* hb = h1 + (size_t)b * O1 * MM + m;
    const float* w  = sw2 + o2 * O1;
    float acc = 0.f;
    #pragma unroll 8
    for (int c = 0; c < O1; c++){
        float v = hb[(size_t)c * MM] * sc[c] + bi[c];
        v = v > 0.f ? v : 0.f;
        acc += w[c] * v;
    }
    h2[t] = acc;
    float s = acc, s2 = acc * acc;
    for (int off = 32; off; off >>= 1){ s += __shfl_down(s, off); s2 += __shfl_down(s2, off); }
    __shared__ float ls[8];
    int lane = tid & 63, wid = tid >> 6;
    if (lane == 0){ ls[wid] = s; ls[4 + wid] = s2; }
    __syncthreads();
    if (tid == 0){
        atomicAdd(&stats2[2*o2],   ls[0]+ls[1]+ls[2]+ls[3]);
        atomicAdd(&stats2[2*o2+1], ls[4]+ls[5]+ls[6]+ls[7]);
    }
}

__global__ void k_fin2(const float* __restrict__ stats2, const float* __restrict__ sg2,
                       const float* __restrict__ sb2, float* __restrict__ scb2){
    int t = threadIdx.x;
    if (t < 3){
        const float invn = 1.f / (BB * MM);
        float mean = stats2[2*t] * invn;
        float var  = fmaxf(stats2[2*t+1] * invn - mean * mean, 0.f);
        float rs   = 1.f / sqrtf(var + 1e-5f);
        float s    = rs * sg2[t];
        float b    = sb2[t] - mean * s;
        if (!isfinite(s) || !isfinite(b)){ s = 1.f; b = 0.f; }
        scb2[t] = s; scb2[4 + t] = b;
    }
}

// ---------------- ball query ----------------
__global__ __launch_bounds__(256) void k_ballq(const float* __restrict__ fxyz,
                                               const float* __restrict__ h2,
                                               const float* __restrict__ scb2,
                                               const float* __restrict__ bxyz,
                                               float* __restrict__ nxyz,
                                               int* __restrict__ idxbuf){
    int q    = blockIdx.x * 4 + (threadIdx.x >> 6);
    int lane = threadIdx.x & 63;
    int b = q >> 10, m = q & (MM - 1);
    float nx[3];
    #pragma unroll
    for (int c = 0; c < 3; c++){
        float v = h2[((size_t)b * 3 + c) * MM + m] * scb2[c] + scb2[4 + c];
        v = v > 0.f ? v : 0.f;
        nx[c] = fxyz[(size_t)q * 3 + c] + v;
    }
    if (lane == 0){
        nxyz[q*3+0] = nx[0]; nxyz[q*3+1] = nx[1]; nxyz[q*3+2] = nx[2];
    }
    const float* bx = bxyz + (size_t)b * NN * 3;
    int have = 0, firstj = 0;
    int* out = idxbuf + (size_t)q * KK;
    for (int j0 = 0; j0 < NN && have < KK; j0 += 64){
        int j = j0 + lane;
        float dx = bx[j*3+0] - nx[0];
        float dy = bx[j*3+1] - nx[1];
        float dz = bx[j*3+2] - nx[2];
        float d2 = dx*dx + dy*dy + dz*dz;
        bool pred = d2 < 1.0f;
        unsigned long long mask = __ballot(pred);
        if (mask){
            if (have == 0) firstj = j0 + (__ffsll((unsigned long long)mask) - 1);
            if (pred){
                int rank = __popcll(mask & ((1ull << lane) - 1ull));
                int pos = have + rank;
                if (pos < KK) out[pos] = j;
            }
            have += (int)__popcll(mask);
        }
    }
    if (have < KK){
        int fill = (have > 0) ? firstj : 0;
        for (int p = have + lane; p < KK; p += 64) out[p] = fill;
    }
}

// ---------------- idx2 / xyzdiff ----------------
__global__ __launch_bounds__(256) void k_xyzd(const int* __restrict__ idxbuf,
                                              const float* __restrict__ bxyz,
                                              const float* __restrict__ nxyz,
                                              int* __restrict__ idx2,
                                              float4* __restrict__ xyzd){
    int l = blockIdx.x * 256 + threadIdx.x;
    int b = l >> 15;
    int q = l >> 5;
    int j = idxbuf[l];
    idx2[l] = b * NN + j;
    const float* p = bxyz + ((size_t)b * NN + j) * 3;
    xyzd[l] = make_float4(p[0] - nxyz[q*3+0], p[1] - nxyz[q*3+1], p[2] - nxyz[q*3+2], 0.f);
}

// ---------------- transpose (B,C,N) -> (B,N,C) f32, flag-aware ----------------
__global__ __launch_bounds__(256) void k_transp(const void* __restrict__ bfv,
                                                const int* __restrict__ flag,
                                                float* __restrict__ ft){
    __shared__ float tile[32][33];
    int f = *flag;
    int bid = blockIdx.x;
    int nt = bid & 511;
    int ct = (bid >> 9) & 7;
    int b  = bid >> 12;
    int tx = threadIdx.x & 31, ty = threadIdx.x >> 5;
    size_t base = ((size_t)b * CC + ct * 32) * NN + nt * 32;
    #pragma unroll
    for (int r = 0; r < 32; r += 8)
        tile[ty + r][tx] = anyf(bfv, base + (size_t)(ty + r) * NN + tx, f);
    __syncthreads();
    float* dst = ft + ((size_t)b * NN + nt * 32) * CC + ct * 32;
    #pragma unroll
    for (int r = 0; r < 32; r += 8) dst[(size_t)(ty + r) * CC + tx] = tile[tx][ty + r];
}

// ---------------- weight prep: w1 -> bf16 hi/lo planes + xyz part ----------------
__global__ void k_wprep(const float* __restrict__ w1,
                        unsigned short* __restrict__ w1h,
                        unsigned short* __restrict__ w1l,
                        float4* __restrict__ w1xp){
    int t = blockIdx.x * 256 + threadIdx.x;
    int o = t >> 8, c = t & 255;
    float f = w1[o * 259 + 3 + c];
    unsigned u = __float_as_uint(f);
    unsigned hh = u & 0xFFFF0000u;
    w1h[t] = (unsigned short)(hh >> 16);
    float f2 = f - __uint_as_float(hh);
    w1l[t] = (unsigned short)(__float_as_uint(f2) >> 16);
    if (t < 512) w1xp[t] = make_float4(w1[t*259], w1[t*259+1], w1[t*259+2], 0.f);
}

// ---------------- generic f32 -> bf16 hi/lo split ----------------
__global__ __launch_bounds__(256) void k_wsplit(const float* __restrict__ src,
                                                unsigned short* __restrict__ h,
                                                unsigned short* __restrict__ l, int n){
    int t = blockIdx.x * 256 + threadIdx.x;
    if (t >= n) return;
    float f = src[t];
    unsigned u = __float_as_uint(f);
    unsigned hh = u & 0xFFFF0000u;
    h[t] = (unsigned short)(hh >> 16);
    float f2 = f - __uint_as_float(hh);
    l[t] = (unsigned short)(__float_as_uint(f2) >> 16);
}

// ---------------- MFMA split-bf16 GEMM, templated ----------------
// Y[l][o] = sum_c A[o][c] * X'[l][c]
//   XM=0: X' = X (row-major [l][Cs]), optionally BN+ReLU via scb
//   XM=1: X'[l][c] = relu(bn1(z[idx2[Lbase+l]][c] + xyzd[Lbase+l]·w1xp[c]))  (scb = BN1)
//   OM=0: write Y for rows l0+128<=Lwrite; accumulate stats (if non-null)
//   OM=1: accumulate stats AND write per-q-group raw max/min of y over k (y3mx/y3mn)
// A is pre-split into bf16 hi/lo planes (Ah/Al). Accuracy: ah*bh+ah*bl+al*bh (~2^-16).
// Tile 128(o) x 128(l) x 32(c), 4 waves, LDS q-XOR swizzled (conflict-free, round-3).
__device__ __forceinline__ void split4(float x, float y, float z_, float w_,
                                       unsigned &h0, unsigned &h1,
                                       unsigned &lo0, unsigned &lo1){
    unsigned ux = __float_as_uint(x), uy = __float_as_uint(y);
    unsigned uz = __float_as_uint(z_), uw = __float_as_uint(w_);
    unsigned hx = ux & 0xFFFF0000u, hy = uy & 0xFFFF0000u;
    unsigned hz = uz & 0xFFFF0000u, hw = uw & 0xFFFF0000u;
    h0 = (hx >> 16) | hy;
    h1 = (hz >> 16) | hw;
    float rx = x  - __uint_as_float(hx);
    float ry = y  - __uint_as_float(hy);
    float rz = z_ - __uint_as_float(hz);
    float rw = w_ - __uint_as_float(hw);
    lo0 = (__float_as_uint(rx) >> 16) | (__float_as_uint(ry) & 0xFFFF0000u);
    lo1 = (__float_as_uint(rz) >> 16) | (__float_as_uint(rw) & 0xFFFF0000u);
}

template<int XM, int OM>
__global__ __launch_bounds__(256) void k_gemm(const unsigned short* __restrict__ Ah,
                                              const unsigned short* __restrict__ Al,
                                              const float* __restrict__ X,
                                              int Cs,
                                              const float* __restrict__ scb,
                                              const int* __restrict__ idx2,
                                              const float4* __restrict__ xyzd,
                                              const float4* __restrict__ w1xp,
                                              int Lbase,
                                              float* __restrict__ Y,
                                              int Lwrite,
                                              float* __restrict__ y3mx,
                                              float* __restrict__ y3mn,
                                              double* __restrict__ stats){
    __shared__ short lds[16384];
    char* ldsb = (char*)lds;

    const int tid  = threadIdx.x;
    const int lane = tid & 63;
    const int w    = tid >> 6;
    const int wo   = (w >> 1) * 64;
    const int wl   = (w & 1) * 64;

    int bid = blockIdx.x;
    {
        int cpx = gridDim.x >> 3;             // grid % 8 == 0 always
        bid = (bid & 7) * cpx + (bid >> 3);
    }
    const int o0 = (bid & 3) * 128;
    const int l0 = (bid >> 2) * 128;

    const int o_loc  = tid >> 3;          // 0..31 (row handled, +32*i)
    const int q      = (tid & 7) >> 1;    // col block
    const int h      = tid & 1;
    const int colOff = q * 8 + h * 4;
    const int wbase  = ((o_loc >> 4) * 1024) + (((o_loc & 15) * 16) ^ (q << 5)) + (q << 8) + h * 8;
    const int roff   = (((lane & 15) * 16) ^ ((lane >> 4) << 5)) + ((lane >> 4) << 8);

    const unsigned short* Ahp = Ah + (size_t)(o0 + o_loc) * Cs + colOff;
    const unsigned short* Alp = Al + (size_t)(o0 + o_loc) * Cs + colOff;

    // X row descriptors
    int   rI[4];
    float ddx[4], ddy[4], ddz[4];
    const float* Xp = nullptr;
    if (XM == 1){
        #pragma unroll
        for (int i = 0; i < 4; i++){
            int lg = Lbase + l0 + o_loc + 32 * i;
            rI[i] = idx2[lg];
            float4 dd = xyzd[lg];
            ddx[i] = dd.x; ddy[i] = dd.y; ddz[i] = dd.z;
        }
    } else {
        Xp = X + (size_t)(l0 + o_loc) * Cs + colOff;
    }

    f4 acc[4][4];
    #pragma unroll
    for (int i = 0; i < 4; i++)
        #pragma unroll
        for (int j = 0; j < 4; j++)
            acc[i][j] = f4{0.f, 0.f, 0.f, 0.f};

    uint2  rah[4], ral[4];
    float4 rx[4];
    #pragma unroll
    for (int i = 0; i < 4; i++){
        rah[i] = *(const uint2*)(Ahp + (size_t)(32 * i) * Cs);
        ral[i] = *(const uint2*)(Alp + (size_t)(32 * i) * Cs);
        if (XM == 1) rx[i] = *(const float4*)(X + (size_t)rI[i] * FF + colOff);
        else         rx[i] = *(const float4*)(Xp + (size_t)(32 * i) * Cs);
    }

    for (int c0 = 0; c0 < Cs; c0 += 32){
        unsigned xh0[4], xh1[4], xL0[4], xL1[4];
        float4 sc4, bi4;
        if (scb){
            sc4 = *(const float4*)(scb + c0 + colOff);
            bi4 = *(const float4*)(scb + Cs + c0 + colOff);
        }
        float4 wv0, wv1, wv2, wv3;
        if (XM == 1){
            wv0 = w1xp[c0 + colOff + 0];
            wv1 = w1xp[c0 + colOff + 1];
            wv2 = w1xp[c0 + colOff + 2];
            wv3 = w1xp[c0 + colOff + 3];
        }
        #pragma unroll
        for (int i = 0; i < 4; i++){
            float vx = rx[i].x, vy = rx[i].y, vz = rx[i].z, vw = rx[i].w;
            if (XM == 1){
                vx += ddx[i]*wv0.x + ddy[i]*wv0.y + ddz[i]*wv0.z;
                vy += ddx[i]*wv1.x + ddy[i]*wv1.y + ddz[i]*wv1.z;
                vz += ddx[i]*wv2.x + ddy[i]*wv2.y + ddz[i]*wv2.z;
                vw += ddx[i]*wv3.x + ddy[i]*wv3.y + ddz[i]*wv3.z;
            }
            if (scb){
                vx = fmaxf(vx * sc4.x + bi4.x, 0.f);
                vy = fmaxf(vy * sc4.y + bi4.y, 0.f);
                vz = fmaxf(vz * sc4.z + bi4.z, 0.f);
                vw = fmaxf(vw * sc4.w + bi4.w, 0.f);
            }
            split4(vx, vy, vz, vw, xh0[i], xh1[i], xL0[i], xL1[i]);
        }
        __syncthreads();   // prev iteration's fragment reads done
        #pragma unroll
        for (int i = 0; i < 4; i++){
            int off = wbase + i * 2048;
            *(uint2*)(ldsb + off)          = rah[i];
            *(uint2*)(ldsb + 8192  + off)  = ral[i];
            *(uint2*)(ldsb + 16384 + off)  = make_uint2(xh0[i], xh1[i]);
            *(uint2*)(ldsb + 24576 + off)  = make_uint2(xL0[i], xL1[i]);
        }
        __syncthreads();
        if (c0 + 32 < Cs){
            #pragma unroll
            for (int i = 0; i < 4; i++){
                rah[i] = *(const uint2*)(Ahp + (size_t)(32 * i) * Cs + (c0 + 32));
                ral[i] = *(const uint2*)(Alp + (size_t)(32 * i) * Cs + (c0 + 32));
                if (XM == 1) rx[i] = *(const float4*)(X + (size_t)rI[i] * FF + colOff + (c0 + 32));
                else         rx[i] = *(const float4*)(Xp + (size_t)(32 * i) * Cs + (c0 + 32));
            }
        }
        b8 bhf[4], blf[4];
        #pragma unroll
        for (int ni = 0; ni < 4; ni++){
            int f = (wl >> 4) + ni;
            bhf[ni] = *(const b8*)(ldsb + 16384 + f * 1024 + roff);
            blf[ni] = *(const b8*)(ldsb + 24576 + f * 1024 + roff);
        }
        #pragma unroll
        for (int mi = 0; mi < 4; mi++){
            int f = (wo >> 4) + mi;
            b8 ahf = *(const b8*)(ldsb + f * 1024 + roff);
            b8 alf = *(const b8*)(ldsb + 8192 + f * 1024 + roff);
            #pragma unroll
            for (int ni = 0; ni < 4; ni++){
                acc[mi][ni] = __builtin_amdgcn_mfma_f32_16x16x32_bf16(ahf, bhf[ni], acc[mi][ni], 0, 0, 0);
                acc[mi][ni] = __builtin_amdgcn_mfma_f32_16x16x32_bf16(ahf, blf[ni], acc[mi][ni], 0, 0, 0);
                acc[mi][ni] = __builtin_amdgcn_mfma_f32_16x16x32_bf16(alf, bhf[ni], acc[mi][ni], 0, 0, 0);
            }
        }
    }

    // D layout: o = wo + mi*16 + 4*(lane>>4) + r,  l = wl + ni*16 + (lane&15)
    if (OM == 0){
        if (Y && (l0 + 128 <= Lwrite)){
            #pragma unroll
            for (int mi = 0; mi < 4; mi++){
                #pragma unroll
                for (int ni = 0; ni < 4; ni++){
                    int o = o0 + wo + mi * 16 + 4 * (lane >> 4);
                    int l = l0 + wl + ni * 16 + (lane & 15);
                    *(float4*)(Y + (size_t)l * FF + o) =
                        make_float4(acc[mi][ni][0], acc[mi][ni][1], acc[mi][ni][2], acc[mi][ni][3]);
                }
            }
        }
    }
    if (stats){
        int slot_s = blockIdx.x & (NSLOT - 1);
        double* sp = stats + (size_t)slot_s * FF * 2;
        #pragma unroll
        for (int mi = 0; mi < 4; mi++){
            float s1[4] = {0,0,0,0}, s2[4] = {0,0,0,0};
            #pragma unroll
            for (int ni = 0; ni < 4; ni++){
                #pragma unroll
                for (int r = 0; r < 4; r++){
                    float v = acc[mi][ni][r];
                    s1[r] += v; s2[r] += v * v;
                }
            }
            #pragma unroll
            for (int off = 8; off; off >>= 1){
                #pragma unroll
                for (int r = 0; r < 4; r++){
                    s1[r] += __shfl_down(s1[r], off, 16);
                    s2[r] += __shfl_down(s2[r], off, 16);
                }
            }
            if ((lane & 15) == 0){
                int o = o0 + wo + mi * 16 + 4 * (lane >> 4);
                #pragma unroll
                for (int r = 0; r < 4; r++){
                    atomicAdd(&sp[2 * (o + r)],     (double)s1[r]);
                    atomicAdd(&sp[2 * (o + r) + 1], (double)s2[r]);
                }
            }
        }
    }
    if (OM == 1){
        // raw per-q-group max/min over k: q-group g covers l = wl + g*32 + [0,32)
        #pragma unroll
        for (int mi = 0; mi < 4; mi++){
            #pragma unroll
            for (int g = 0; g < 2; g++){
                float vmx[4], vmn[4];
                #pragma unroll
                for (int r = 0; r < 4; r++){
                    float a0 = acc[mi][2*g][r], a1 = acc[mi][2*g+1][r];
                    vmx[r] = fmaxf(a0, a1); vmn[r] = fminf(a0, a1);
                }
                #pragma unroll
                for (int off = 8; off; off >>= 1){
                    #pragma unroll
                    for (int r = 0; r < 4; r++){
                        vmx[r] = fmaxf(vmx[r], __shfl_down(vmx[r], off, 16));
                        vmn[r] = fminf(vmn[r], __shfl_down(vmn[r], off, 16));
                    }
                }
                if ((lane & 15) == 0){
                    int qg = (Lbase + l0 + wl) / 32 + g;
                    #pragma unroll
                    for (int r = 0; r < 4; r++){
                        int o = o0 + wo + mi * 16 + 4 * (lane >> 4) + r;
                        y3mx[(size_t)qg * FF + o] = vmx[r];
                        y3mn[(size_t)qg * FF + o] = vmn[r];
                    }
                }
            }
        }
    }
}

// ---------------- finalize BN ----------------
__global__ void k_finL(const double* __restrict__ stats, const float* __restrict__ g,
                       const float* __restrict__ bt, float* __restrict__ scb){
    int o = blockIdx.x * 256 + threadIdx.x;
    double s = 0.0, s2 = 0.0;
    for (int k = 0; k < NSLOT; k++){
        s  += stats[((size_t)k * FF + o) * 2];
        s2 += stats[((size_t)k * FF + o) * 2 + 1];
    }
    double mean = s / (double)LTOT;
    double var  = s2 / (double)LTOT - mean * mean;
    if (!(var > 0.0)) var = 0.0;
    double rs = 1.0 / sqrt(var + 1e-5);
    double sc = rs * (double)g[o];
    double bi = (double)bt[o] - mean * sc;
    float scf = (float)sc, bif = (float)bi;
    if (!isfinite(scf) || !isfinite(bif)){ scf = 1.f; bif = 0.f; }
    scb[o] = scf;
    scb[FF + o] = bif;
}

// ---------------- y1 stats ----------------
__global__ __launch_bounds__(256) void k_y1stats(const float* __restrict__ z,
                                                 const int* __restrict__ idx2,
                                                 const float4* __restrict__ xyzd,
                                                 const float4* __restrict__ w1xp,
                                                 double* __restrict__ stats){
    int tid = threadIdx.x, bid = blockIdx.x;
    int o1 = tid, o2 = tid + 256;
    float4 wa = w1xp[o1], wb = w1xp[o2];
    double s1a=0, s2a=0, s1b=0, s2b=0;
    for (int p = 0; p < LTOT/2048; p++){
        int l = bid + p * 2048;
        int r = idx2[l];
        float4 d = xyzd[l];
        const float* zr = z + (size_t)r * FF;
        float ya = zr[o1] + d.x*wa.x + d.y*wa.y + d.z*wa.z;
        float yb = zr[o2] + d.x*wb.x + d.y*wb.y + d.z*wb.z;
        s1a += ya; s2a += (double)ya*ya;
        s1b += yb; s2b += (double)yb*yb;
    }
    int slot = bid & (NSLOT - 1);
    double* sp = stats + (size_t)slot * FF * 2;
    atomicAdd(&sp[2*o1],   s1a); atomicAdd(&sp[2*o1+1], s2a);
    atomicAdd(&sp[2*o2],   s1b); atomicAdd(&sp[2*o2+1], s2b);
}

// ---------------- BN3 + final selection from stored max/min ----------------
__global__ __launch_bounds__(256) void k_bn3max(const float* __restrict__ mx,
                                                const float* __restrict__ mn,
                                                const float* __restrict__ scb,
                                                float* __restrict__ out){
    int t = blockIdx.x * 256 + threadIdx.x;    // grid 8192 -> 2,097,152 = 4096*512
    int o = t & (FF - 1);
    float sc = scb[o], bi = scb[FF + o];
    float v = sc >= 0.f ? mx[t] : mn[t];
    out[t] = fmaxf(sc * v + bi, 0.f);
}

// ---------------- stage diagnostics (float sentinel, fires only on unhealthy) ----------------
__global__ __launch_bounds__(256) void k_diag(const float* __restrict__ ff,
                                              const float* __restrict__ w1f,
                                              const float* __restrict__ featT,
                                              const float* __restrict__ z,
                                              const float* __restrict__ xyzdf,
                                              const float* __restrict__ scb1,
                                              const float* __restrict__ scbL2,
                                              const float* __restrict__ scbL3,
                                              const float* __restrict__ y3,
                                              float* __restrict__ out){
    __shared__ float red[4];
    int tid = threadIdx.x;
    int bad = 0, isn = 0;
    const float* arr[9] = {ff, w1f, featT, z, xyzdf, scb1, scbL2, scbL3, y3};
    const int   len[9] = {4096, 4096, 8192, 8192, 4096, 1024, 1024, 1024, 8192};
    for (int k = 0; k < 9; k++){
        float s = 0.f;
        const float* a = arr[k];
        for (int i = tid; i < len[k]; i += 256) s += fabsf(a[i]);
        for (int off = 32; off; off >>= 1) s += __shfl_down(s, off);
        if ((tid & 63) == 0) red[tid >> 6] = s;
        __syncthreads();
        float t = red[0] + red[1] + red[2] + red[3];
        __syncthreads();
        if (bad == 0 && !(t > 1e-6f && t < 1e15f)){
            bad = k + 1;
            isn = isfinite(t) ? 0 : 1;
        }
    }
    if (tid == 0 && bad) out[0] = 512.f * bad + 256.f * isn;
}

extern "C" void kernel_launch(void* const* d_in, const int* in_sizes, int n_in,
                              void* d_out, int out_size, void* d_ws, size_t ws_size,
                              hipStream_t stream) {
    static const int NSZ[19] = {12288, 1048576, 196608, 16777216, 32768, 128, 128,
                                384, 3, 3, 132608, 512, 512, 262144, 512, 512,
                                262144, 512, 512};
    float* out = (float*)d_out;   // OUTPUT IS FLOAT32

    char* w = (char*)d_ws;
    size_t off = 0;
    auto take = [&](size_t bytes)->size_t{
        size_t r = off; off += (bytes + 255) & ~(size_t)255; return r;
    };
    size_t o_stats1  = take(256 * 4);
    size_t o_stats2  = take(8 * 4);
    size_t o_statsA  = take((size_t)NSLOT * FF * 2 * 8);
    size_t o_statsL2 = take((size_t)NSLOT * FF * 2 * 8);
    size_t o_statsL3 = take((size_t)NSLOT * FF * 2 * 8);
    size_t zero_end  = off;
    size_t o_flags   = take(19 * 4);
    size_t o_cv[19];
    for (int i = 0; i < 19; i++){
        if (i == 3){ o_cv[i] = 0; continue; }
        o_cv[i] = take((size_t)NSZ[i] * 4);
    }
    size_t o_scb2    = take(8 * 4);
    size_t o_scb1    = take(FF * 2 * 4);
    size_t o_scbL2   = take(FF * 2 * 4);
    size_t o_scbL3   = take(FF * 2 * 4);
    size_t o_h1      = take((size_t)BB * O1 * MM * 4);
    size_t o_h2      = take((size_t)BB * 3 * MM * 4);
    size_t o_nxyz    = take((size_t)BB * MM * 3 * 4);
    size_t o_idx     = take((size_t)LTOT * 4);
    size_t o_idx2    = take((size_t)LTOT * 4);
    size_t o_xyzd    = take((size_t)LTOT * 16);
    size_t o_w1h     = take((size_t)FF * CC * 2);
    size_t o_w1l     = take((size_t)FF * CC * 2);
    size_t o_w2h     = take((size_t)FF * FF * 2);
    size_t o_w2l     = take((size_t)FF * FF * 2);
    size_t o_w3h     = take((size_t)FF * FF * 2);
    size_t o_w3l     = take((size_t)FF * FF * 2);
    size_t o_w1xp    = take((size_t)FF * 16);
    size_t o_y3mx    = take((size_t)BB * MM * FF * 4);    // 8.4 MB
    size_t o_y3mn    = take((size_t)BB * MM * FF * 4);    // 8.4 MB
    size_t o_z       = take((size_t)BB * NN * FF * 4);    // 134 MB
    size_t o_featT   = take((size_t)BB * NN * CC * 4);    // 67 MB, dead after z-GEMM
    (void)n_in; (void)in_sizes; (void)out_size;

    // adaptive t2 chunk storage in [o_featT, ws_size)
    const size_t chb = (size_t)CH * FF * 4;               // 33.5 MB per chunk
    size_t avail = ws_size > o_featT ? ws_size - o_featT : 0;
    int S; bool full;
    if (avail >= (size_t)NCH2 * chb){ S = NCH2; full = true; }
    else {
        long s = (long)(avail / chb) - 1;                 // reserve 1 chunk for scratch
        if (s < 0) s = 0; if (s > NCH2 - 1) s = NCH2 - 1;
        S = (int)s; full = false;
    }
    const int Lwrite = S * CH;

    float*  stats1  = (float*) (w + o_stats1);
    float*  stats2  = (float*) (w + o_stats2);
    double* statsA  = (double*)(w + o_statsA);
    double* statsL2 = (double*)(w + o_statsL2);
    double* statsL3 = (double*)(w + o_statsL3);
    int*    flags   = (int*)   (w + o_flags);
    float*  scb2    = (float*) (w + o_scb2);
    float*  scb1    = (float*) (w + o_scb1);
    float*  scbL2   = (float*) (w + o_scbL2);
    float*  scbL3   = (float*) (w + o_scbL3);
    float*  h1      = (float*) (w + o_h1);
    float*  h2      = (float*) (w + o_h2);
    float*  nxyz    = (float*) (w + o_nxyz);
    int*    idxbuf  = (int*)   (w + o_idx);
    int*    idx2    = (int*)   (w + o_idx2);
    float4* xyzd    = (float4*)(w + o_xyzd);
    unsigned short* w1h = (unsigned short*)(w + o_w1h);
    unsigned short* w1l = (unsigned short*)(w + o_w1l);
    unsigned short* w2h = (unsigned short*)(w + o_w2h);
    unsigned short* w2l = (unsigned short*)(w + o_w2l);
    unsigned short* w3h = (unsigned short*)(w + o_w3h);
    unsigned short* w3l = (unsigned short*)(w + o_w3l);
    float4* w1xp    = (float4*)(w + o_w1xp);
    float*  y3mx    = (float*) (w + o_y3mx);
    float*  y3mn    = (float*) (w + o_y3mn);
    float*  z       = (float*) (w + o_z);
    float*  featT   = (float*) (w + o_featT);
    float*  t2scr   = featT;                                        // scratch chunk
    float*  t2store = full ? featT : featT + (size_t)CH * FF;       // stored rows [0, S*CH)

    hipMemsetAsync(w, 0, zero_end, stream);

    float* cv[19];
    for (int i = 0; i < 19; i++){
        k_det<<<1, 64, 0, stream>>>((const unsigned short*)d_in[i], NSZ[i], flags + i);
        if (i == 3){ cv[i] = nullptr; continue; }
        cv[i] = (float*)(w + o_cv[i]);
    }
    for (int i = 0; i < 19; i++){
        if (i == 3) continue;
        k_cvtf<<<(NSZ[i] + 255) / 256, 256, 0, stream>>>(d_in[i], cv[i], NSZ[i], flags + i);
    }
    float* fx = cv[0], *ffp = cv[1], *bx = cv[2];
    float* sw1f = cv[4], *sg1f = cv[5], *sb1f = cv[6];
    float* sw2f = cv[7], *sg2f = cv[8], *sb2f = cv[9];
    float* w1f = cv[10], *g1f = cv[11], *b1f = cv[12];
    float* w2f = cv[13], *g2f = cv[14], *b2f = cv[15];
    float* w3f = cv[16], *g3f = cv[17], *b3f = cv[18];

    k_mlp1   <<<2048, 256, 0, stream>>>(sw1f, ffp, h1, stats1);
    k_bn1mlp2<<<48,   256, 0, stream>>>(h1, stats1, sg1f, sb1f, sw2f, h2, stats2);
    k_fin2   <<<1,    64,  0, stream>>>(stats2, sg2f, sb2f, scb2);
    k_ballq  <<<BB*MM/4, 256, 0, stream>>>(fx, h2, scb2, bx, nxyz, idxbuf);
    k_xyzd   <<<LTOT/256, 256, 0, stream>>>(idxbuf, bx, nxyz, idx2, xyzd);
    k_transp <<<BB*(CC/32)*(NN/32), 256, 0, stream>>>(d_in[3], flags + 3, featT);
    k_wprep  <<<512, 256, 0, stream>>>(w1f, w1h, w1l, w1xp);
    k_wsplit <<<1024, 256, 0, stream>>>(w2f, w2h, w2l, FF*FF);
    k_wsplit <<<1024, 256, 0, stream>>>(w3f, w3h, w3l, FF*FF);

    // z = featT @ w1^T : (65536 x 256) x (512 x 256)^T -> 65536 x 512
    k_gemm<0,0><<<4 * (BB*NN/128), 256, 0, stream>>>(w1h, w1l, featT, CC, nullptr,
            nullptr, nullptr, nullptr, 0, z, BB*NN, nullptr, nullptr, nullptr);

    k_y1stats<<<2048, 256, 0, stream>>>(z, idx2, xyzd, w1xp, statsA);
    k_finL  <<<2, 256, 0, stream>>>(statsA, g1f, b1f, scb1);

    const int GFULL = 4 * (LTOT/128);   // 4096
    const int GCH   = 4 * (CH/128);     // 512

    // pass 1: full gemm2 (y1 fused) -> statsL2; store t2 rows [0, S*CH)
    k_gemm<1,0><<<GFULL, 256, 0, stream>>>(w2h, w2l, z, FF, scb1,
            idx2, xyzd, w1xp, 0, t2store, Lwrite, nullptr, nullptr, statsL2);
    k_finL <<<2, 256, 0, stream>>>(statsL2, g2f, b2f, scbL2);

    // pass 2: gemm3 over all rows exactly once -> statsL3 + raw per-q max/min
    if (S > 0){
        k_gemm<0,1><<<S * GCH, 256, 0, stream>>>(w3h, w3l, t2store, FF, scbL2,
                nullptr, nullptr, nullptr, 0, nullptr, 0, y3mx, y3mn, statsL3);
    }
    for (int c = S; c < NCH2; c++){
        k_gemm<1,0><<<GCH, 256, 0, stream>>>(w2h, w2l, z, FF, scb1,
                idx2, xyzd, w1xp, c*CH, t2scr, CH, nullptr, nullptr, nullptr);
        k_gemm<0,1><<<GCH, 256, 0, stream>>>(w3h, w3l, t2scr, FF, scbL2,
                nullptr, nullptr, nullptr, c*CH, nullptr, 0, y3mx, y3mn, statsL3);
    }
    k_finL <<<2, 256, 0, stream>>>(statsL3, g3f, b3f, scbL3);

    // pass 3: BN3 + select + relu (exact: relu(sc*v+bi) monotone in v per sign of sc)
    k_bn3max<<<(BB*MM*FF)/256, 256, 0, stream>>>(y3mx, y3mn, scbL3, out);

    k_diag<<<1, 256, 0, stream>>>(ffp, w1f, t2scr, z, (const float*)xyzd,
                                  scb1, scbL2, scbL3, y3mx, out);
}

// Round 6
// 1496.666 us; speedup vs baseline: 4.1566x; 1.1205x over previous
//
#include <hip/hip_runtime.h>
#include <hip/hip_bf16.h>
#include <hip/hip_fp16.h>

#define BB   4
#define NN   16384
#define MM   1024
#define CC   256
#define KK   32
#define O1   128
#define FF   512
#define LTOT (BB*MM*KK)   // 131072
#define NSLOT 64
#define CH   16384
#define NCH2 (LTOT/CH)    // 8

typedef float f4 __attribute__((ext_vector_type(4)));
typedef short b8 __attribute__((ext_vector_type(8)));

struct CvtA {
    const void* src[19];
    unsigned cum[20];     // 256-rounded cumulative element starts (input 3 width 0)
    unsigned dstF[19];    // float-index offset of cv[i] within workspace
    int      nsz[19];
};

__device__ __forceinline__ float bf2f(unsigned short u){
    return __uint_as_float(((unsigned int)u) << 16);
}
__device__ __forceinline__ float anyf(const void* p, size_t i, int f){
    if (f == 1) return bf2f(((const unsigned short*)p)[i]);
    if (f == 2) return __half2float(((const __half*)p)[i]);
    return ((const float*)p)[i];
}

// ---- batched dtype detector: 0=f32, 1=bf16, 2=fp16 (block b -> input b) ----
__global__ void k_det19(CvtA a, int* __restrict__ flags){
    if (threadIdx.x != 0) return;
    int i = blockIdx.x;
    const unsigned short* u = (const unsigned short*)a.src[i];
    int n = a.nsz[i];
    int* flag = flags + i;
    int W = n < 64 ? n : 64;
    bool allz = true;
    for (int k = 0; k < W; k++) if (u[k]){ allz = false; break; }
    if (allz){ *flag = 1; return; }
    if (u[0] == 0x3F80u){ *flag = 1; return; }
    if (u[0] == 0x3C00u){ *flag = 2; return; }
    if (W >= 2){
        unsigned int f0 = ((unsigned int)u[1] << 16) | u[0];
        if (__uint_as_float(f0) == 1.0f){ *flag = 0; return; }
    }
    int ce = 0, co = 0, ne = 0, no_ = 0;
    for (int k = 0; k < W; k++){
        unsigned short x = u[k];
        float v = fabsf(bf2f(x));
        int sane = (x == 0) || (v >= 0.0009765625f && v <= 64.f);
        if (k & 1){ no_++; co += sane; } else { ne++; ce += sane; }
    }
    if (ce * 4 >= ne * 3){ *flag = 1; return; }
    if (co * 4 >= no_ * 3 && ce * 5 < ne * 2){ *flag = 0; return; }
    *flag = 2;
}

// ---- fused converter: one grid covers all inputs via cum[] table ----
__global__ __launch_bounds__(256) void k_cvt19(CvtA a, const int* __restrict__ flags,
                                               float* __restrict__ base){
    unsigned eb = blockIdx.x * 256u;
    int i = 0;
    while (eb >= a.cum[i+1]) i++;
    unsigned tl = eb - a.cum[i] + threadIdx.x;
    if ((int)tl >= a.nsz[i]) return;
    base[a.dstF[i] + tl] = anyf(a.src[i], tl, flags[i]);
}

// ---------------- Stage 1 ----------------
__global__ __launch_bounds__(256) void k_mlp1(const float* __restrict__ sw1,
                                              const float* __restrict__ feat,
                                              float* __restrict__ h1,
                                              float* __restrict__ stats1){
    int t = blockIdx.x * 256 + threadIdx.x;
    int m = t & (MM - 1);
    int o = (t >> 10) & (O1 - 1);
    int b = t >> 17;
    const float* fb = feat + (size_t)b * CC * MM + m;
    const float* w  = sw1 + o * CC;
    float acc = 0.f;
    #pragma unroll 8
    for (int c = 0; c < CC; c++) acc += w[c] * fb[(size_t)c * MM];
    h1[t] = acc;
    float s = acc, s2 = acc * acc;
    for (int off = 32; off; off >>= 1){ s += __shfl_down(s, off); s2 += __shfl_down(s2, off); }
    __shared__ float ls[8];
    int lane = threadIdx.x & 63, wid = threadIdx.x >> 6;
    if (lane == 0){ ls[wid] = s; ls[4 + wid] = s2; }
    __syncthreads();
    if (threadIdx.x == 0){
        atomicAdd(&stats1[2*o],   ls[0]+ls[1]+ls[2]+ls[3]);
        atomicAdd(&stats1[2*o+1], ls[4]+ls[5]+ls[6]+ls[7]);
    }
}

// ---------------- Stage 2 ----------------
__global__ __launch_bounds__(256) void k_bn1mlp2(const float* __restrict__ h1,
                                                 const float* __restrict__ stats1,
                                                 const float* __restrict__ sg1,
                                                 const float* __restrict__ sb1,
                                                 const float* __restrict__ sw2,
                                                 float* __restrict__ h2,
                                                 float* __restrict__ stats2){
    __shared__ float sc[O1], bi[O1];
    int tid = threadIdx.x;
    if (tid < O1){
        const float invn = 1.f / (BB * MM);
        float mean = stats1[2*tid] * invn;
        float var  = fmaxf(stats1[2*tid+1] * invn - mean * mean, 0.f);
        float rs   = 1.f / sqrtf(var + 1e-5f);
        float s    = rs * sg1[tid];
        float b_   = sb1[tid] - mean * s;
        if (!isfinite(s) || !isfinite(b_)){ s = 1.f; b_ = 0.f; }
        sc[tid] = s; bi[tid] = b_;
    }
    __syncthreads();
    int t = blockIdx.x * 256 + tid;
    int m = t & (MM - 1);
    int r = t >> 10; int o2 = r % 3; int b = r / 3;
    const float* hb = h1 + (size_t)b * O1 * MM + m;
    const float* w  = sw2 + o2 * O1;
    float acc = 0.f;
    #pragma unroll 8
    for (int c = 0; c < O1; c++){
        float v = hb[(size_t)c * MM] * sc[c] + bi[c];
        v = v > 0.f ? v : 0.f;
        acc += w[c] * v;
    }
    h2[t] = acc;
    float s = acc, s2 = acc * acc;
    for (int off = 32; off; off >>= 1){ s += __shfl_down(s, off); s2 += __shfl_down(s2, off); }
    __shared__ float ls[8];
    int lane = tid & 63, wid = tid >> 6;
    if (lane == 0){ ls[wid] = s; ls[4 + wid] = s2; }
    __syncthreads();
    if (tid == 0){
        atomicAdd(&stats2[2*o2],   ls[0]+ls[1]+ls[2]+ls[3]);
        atomicAdd(&stats2[2*o2+1], ls[4]+ls[5]+ls[6]+ls[7]);
    }
}

__global__ void k_fin2(const float* __restrict__ stats2, const float* __restrict__ sg2,
                       const float* __restrict__ sb2, float* __restrict__ scb2){
    int t = threadIdx.x;
    if (t < 3){
        const float invn = 1.f / (BB * MM);
        float mean = stats2[2*t] * invn;
        float var  = fmaxf(stats2[2*t+1] * invn - mean * mean, 0.f);
        float rs   = 1.f / sqrtf(var + 1e-5f);
        float s    = rs * sg2[t];
        float b    = sb2[t] - mean * s;
        if (!isfinite(s) || !isfinite(b)){ s = 1.f; b = 0.f; }
        scb2[t] = s; scb2[4 + t] = b;
    }
}

// ---------------- ball query ----------------
__global__ __launch_bounds__(256) void k_ballq(const float* __restrict__ fxyz,
                                               const float* __restrict__ h2,
                                               const float* __restrict__ scb2,
                                               const float* __restrict__ bxyz,
                                               float* __restrict__ nxyz,
                                               int* __restrict__ idxbuf){
    int q    = blockIdx.x * 4 + (threadIdx.x >> 6);
    int lane = threadIdx.x & 63;
    int b = q >> 10, m = q & (MM - 1);
    float nx[3];
    #pragma unroll
    for (int c = 0; c < 3; c++){
        float v = h2[((size_t)b * 3 + c) * MM + m] * scb2[c] + scb2[4 + c];
        v = v > 0.f ? v : 0.f;
        nx[c] = fxyz[(size_t)q * 3 + c] + v;
    }
    if (lane == 0){
        nxyz[q*3+0] = nx[0]; nxyz[q*3+1] = nx[1]; nxyz[q*3+2] = nx[2];
    }
    const float* bx = bxyz + (size_t)b * NN * 3;
    int have = 0, firstj = 0;
    int* out = idxbuf + (size_t)q * KK;
    for (int j0 = 0; j0 < NN && have < KK; j0 += 64){
        int j = j0 + lane;
        float dx = bx[j*3+0] - nx[0];
        float dy = bx[j*3+1] - nx[1];
        float dz = bx[j*3+2] - nx[2];
        float d2 = dx*dx + dy*dy + dz*dz;
        bool pred = d2 < 1.0f;
        unsigned long long mask = __ballot(pred);
        if (mask){
            if (have == 0) firstj = j0 + (__ffsll((unsigned long long)mask) - 1);
            if (pred){
                int rank = __popcll(mask & ((1ull << lane) - 1ull));
                int pos = have + rank;
                if (pos < KK) out[pos] = j;
            }
            have += (int)__popcll(mask);
        }
    }
    if (have < KK){
        int fill = (have > 0) ? firstj : 0;
        for (int p = have + lane; p < KK; p += 64) out[p] = fill;
    }
}

// ---------------- idx2 / xyzdiff ----------------
__global__ __launch_bounds__(256) void k_xyzd(const int* __restrict__ idxbuf,
                                              const float* __restrict__ bxyz,
                                              const float* __restrict__ nxyz,
                                              int* __restrict__ idx2,
                                              float4* __restrict__ xyzd){
    int l = blockIdx.x * 256 + threadIdx.x;
    int b = l >> 15;
    int q = l >> 5;
    int j = idxbuf[l];
    idx2[l] = b * NN + j;
    const float* p = bxyz + ((size_t)b * NN + j) * 3;
    xyzd[l] = make_float4(p[0] - nxyz[q*3+0], p[1] - nxyz[q*3+1], p[2] - nxyz[q*3+2], 0.f);
}

// ---------------- transpose (B,C,N) -> (B,N,C) f32, flag-aware ----------------
__global__ __launch_bounds__(256) void k_transp(const void* __restrict__ bfv,
                                                const int* __restrict__ flag,
                                                float* __restrict__ ft){
    __shared__ float tile[32][33];
    int f = *flag;
    int bid = blockIdx.x;
    int nt = bid & 511;
    int ct = (bid >> 9) & 7;
    int b  = bid >> 12;
    int tx = threadIdx.x & 31, ty = threadIdx.x >> 5;
    size_t base = ((size_t)b * CC + ct * 32) * NN + nt * 32;
    #pragma unroll
    for (int r = 0; r < 32; r += 8)
        tile[ty + r][tx] = anyf(bfv, base + (size_t)(ty + r) * NN + tx, f);
    __syncthreads();
    float* dst = ft + ((size_t)b * NN + nt * 32) * CC + ct * 32;
    #pragma unroll
    for (int r = 0; r < 32; r += 8) dst[(size_t)(ty + r) * CC + tx] = tile[tx][ty + r];
}

// ---------------- weight pack: f32 (o,c) -> MFMA-fragment-linear bf16 hi/lo ----------------
// layout: t = ((of*nK + ks)*64 + lane)*8 + j  holds  W[of*16 + (lane&15)]
//                                                      [ks*32 + (lane>>4)*8 + (j>>2)*4 + (j&3)]
__global__ __launch_bounds__(256) void k_wpack(const float* __restrict__ src,
                                               int stride, int srcOff, int Cs,
                                               unsigned short* __restrict__ hph,
                                               unsigned short* __restrict__ hpl){
    int t = blockIdx.x * 256 + threadIdx.x;
    if (t >= FF * Cs) return;
    int nK = Cs >> 5;
    int j  = t & 7;
    int ln = (t >> 3) & 63;
    int r  = t >> 9;
    int ks = r % nK;
    int of = r / nK;
    int o = of * 16 + (ln & 15);
    int c = ks * 32 + (ln >> 4) * 8 + ((j >> 2) << 2) + (j & 3);
    float f = src[(size_t)o * stride + srcOff + c];
    unsigned u = __float_as_uint(f);
    unsigned hh = u & 0xFFFF0000u;
    hph[t] = (unsigned short)(hh >> 16);
    float f2 = f - __uint_as_float(hh);
    hpl[t] = (unsigned short)(__float_as_uint(f2) >> 16);
}

__global__ void k_w1xyz(const float* __restrict__ w1, float4* __restrict__ w1xp){
    int t = blockIdx.x * 256 + threadIdx.x;
    if (t < FF) w1xp[t] = make_float4(w1[t*259], w1[t*259+1], w1[t*259+2], 0.f);
}

// ---------------- MFMA split-bf16 GEMM, templated ----------------
// Y[l][o] = sum_c A[o][c] * X'[l][c]
//   XM=0: X' = X (row-major [l][Cs]), optionally BN+ReLU via scb
//   XM=1: X'[l][c] = relu(bn1(z[idx2[Lbase+l]][c] + xyzd[Lbase+l]·w1xp[c]))  (scb = BN1)
//   OM=0: write Y for rows l0+128<=Lwrite; accumulate stats (if non-null)
//   OM=1: accumulate stats AND write per-q-group raw max/min of y over k (y3mx/y3mn)
// A comes PRE-PACKED in fragment-linear bf16 hi/lo (k_wpack) -> loaded straight from
// global (L2-hot, coalesced lane*16), double-buffered in regs. LDS holds X only (16 KB).
__device__ __forceinline__ void split4(float x, float y, float z_, float w_,
                                       unsigned &h0, unsigned &h1,
                                       unsigned &lo0, unsigned &lo1){
    unsigned ux = __float_as_uint(x), uy = __float_as_uint(y);
    unsigned uz = __float_as_uint(z_), uw = __float_as_uint(w_);
    unsigned hx = ux & 0xFFFF0000u, hy = uy & 0xFFFF0000u;
    unsigned hz = uz & 0xFFFF0000u, hw = uw & 0xFFFF0000u;
    h0 = (hx >> 16) | hy;
    h1 = (hz >> 16) | hw;
    float rx = x  - __uint_as_float(hx);
    float ry = y  - __uint_as_float(hy);
    float rz = z_ - __uint_as_float(hz);
    float rw = w_ - __uint_as_float(hw);
    lo0 = (__float_as_uint(rx) >> 16) | (__float_as_uint(ry) & 0xFFFF0000u);
    lo1 = (__float_as_uint(rz) >> 16) | (__float_as_uint(rw) & 0xFFFF0000u);
}

template<int XM, int OM>
__global__ __launch_bounds__(256) void k_gemm(const unsigned short* __restrict__ Aph,
                                              const unsigned short* __restrict__ Apl,
                                              const float* __restrict__ X,
                                              int Cs,
                                              const float* __restrict__ scb,
                                              const int* __restrict__ idx2,
                                              const float4* __restrict__ xyzd,
                                              const float4* __restrict__ w1xp,
                                              int Lbase,
                                              float* __restrict__ Y,
                                              int Lwrite,
                                              float* __restrict__ y3mx,
                                              float* __restrict__ y3mn,
                                              double* __restrict__ stats){
    __shared__ short lds[8192];          // Xhi [0,8K) Xlo [8K,16K)
    char* ldsb = (char*)lds;

    const int tid  = threadIdx.x;
    const int lane = tid & 63;
    const int w    = tid >> 6;
    const int wo   = (w >> 1) * 64;
    const int wl   = (w & 1) * 64;

    int bid = blockIdx.x;
    {
        int cpx = gridDim.x >> 3;             // grid % 8 == 0 always
        bid = (bid & 7) * cpx + (bid >> 3);
    }
    const int o0 = (bid & 3) * 128;
    const int l0 = (bid >> 2) * 128;

    const int o_loc  = tid >> 3;          // 0..31 (row handled, +32*i)
    const int q      = (tid & 7) >> 1;    // col block
    const int h      = tid & 1;
    const int colOff = q * 8 + h * 4;
    const int wbase  = ((o_loc >> 4) * 1024) + (((o_loc & 15) * 16) ^ (q << 5)) + (q << 8) + h * 8;
    const int roff   = (((lane & 15) * 16) ^ ((lane >> 4) << 5)) + ((lane >> 4) << 8);

    // A fragment addressing (packed): frag index fbase+mi, K-step ks -> byte off
    const int nK    = Cs >> 5;
    const int fbase = (o0 + wo) >> 4;
    const int aLane = lane * 16;

    // X row descriptors
    int   rI[4];
    float ddx[4], ddy[4], ddz[4];
    const float* Xp = nullptr;
    if (XM == 1){
        #pragma unroll
        for (int i = 0; i < 4; i++){
            int lg = Lbase + l0 + o_loc + 32 * i;
            rI[i] = idx2[lg];
            float4 dd = xyzd[lg];
            ddx[i] = dd.x; ddy[i] = dd.y; ddz[i] = dd.z;
        }
    } else {
        Xp = X + (size_t)(l0 + o_loc) * Cs + colOff;
    }

    f4 acc[4][4];
    #pragma unroll
    for (int i = 0; i < 4; i++)
        #pragma unroll
        for (int j = 0; j < 4; j++)
            acc[i][j] = f4{0.f, 0.f, 0.f, 0.f};

    float4 rx[4];
    b8 ahf[4], alf[4];
    #pragma unroll
    for (int i = 0; i < 4; i++){
        if (XM == 1) rx[i] = *(const float4*)(X + (size_t)rI[i] * FF + colOff);
        else         rx[i] = *(const float4*)(Xp + (size_t)(32 * i) * Cs);
        int ab = ((fbase + i) * nK) << 10;
        ahf[i] = *(const b8*)((const char*)Aph + ab + aLane);
        alf[i] = *(const b8*)((const char*)Apl + ab + aLane);
    }

    for (int c0 = 0; c0 < Cs; c0 += 32){
        unsigned xh0[4], xh1[4], xL0[4], xL1[4];
        float4 sc4, bi4;
        if (scb){
            sc4 = *(const float4*)(scb + c0 + colOff);
            bi4 = *(const float4*)(scb + Cs + c0 + colOff);
        }
        float4 wv0, wv1, wv2, wv3;
        if (XM == 1){
            wv0 = w1xp[c0 + colOff + 0];
            wv1 = w1xp[c0 + colOff + 1];
            wv2 = w1xp[c0 + colOff + 2];
            wv3 = w1xp[c0 + colOff + 3];
        }
        #pragma unroll
        for (int i = 0; i < 4; i++){
            float vx = rx[i].x, vy = rx[i].y, vz = rx[i].z, vw = rx[i].w;
            if (XM == 1){
                vx += ddx[i]*wv0.x + ddy[i]*wv0.y + ddz[i]*wv0.z;
                vy += ddx[i]*wv1.x + ddy[i]*wv1.y + ddz[i]*wv1.z;
                vz += ddx[i]*wv2.x + ddy[i]*wv2.y + ddz[i]*wv2.z;
                vw += ddx[i]*wv3.x + ddy[i]*wv3.y + ddz[i]*wv3.z;
            }
            if (scb){
                vx = fmaxf(vx * sc4.x + bi4.x, 0.f);
                vy = fmaxf(vy * sc4.y + bi4.y, 0.f);
                vz = fmaxf(vz * sc4.z + bi4.z, 0.f);
                vw = fmaxf(vw * sc4.w + bi4.w, 0.f);
            }
            split4(vx, vy, vz, vw, xh0[i], xh1[i], xL0[i], xL1[i]);
        }
        __syncthreads();   // prev iteration's fragment reads done
        #pragma unroll
        for (int i = 0; i < 4; i++){
            int off = wbase + i * 2048;
            *(uint2*)(ldsb + off)         = make_uint2(xh0[i], xh1[i]);
            *(uint2*)(ldsb + 8192 + off)  = make_uint2(xL0[i], xL1[i]);
        }
        __syncthreads();
        // prefetch next K-step (X rows + A fragments) — latency hides under MFMAs
        b8 nah[4], nal[4];
        if (c0 + 32 < Cs){
            int ks1 = (c0 >> 5) + 1;
            #pragma unroll
            for (int i = 0; i < 4; i++){
                if (XM == 1) rx[i] = *(const float4*)(X + (size_t)rI[i] * FF + colOff + (c0 + 32));
                else         rx[i] = *(const float4*)(Xp + (size_t)(32 * i) * Cs + (c0 + 32));
                int ab = (((fbase + i) * nK + ks1)) << 10;
                nah[i] = *(const b8*)((const char*)Aph + ab + aLane);
                nal[i] = *(const b8*)((const char*)Apl + ab + aLane);
            }
        }
        b8 bhf[4], blf[4];
        #pragma unroll
        for (int ni = 0; ni < 4; ni++){
            int f = (wl >> 4) + ni;
            bhf[ni] = *(const b8*)(ldsb + f * 1024 + roff);
            blf[ni] = *(const b8*)(ldsb + 8192 + f * 1024 + roff);
        }
        #pragma unroll
        for (int mi = 0; mi < 4; mi++){
            #pragma unroll
            for (int ni = 0; ni < 4; ni++){
                acc[mi][ni] = __builtin_amdgcn_mfma_f32_16x16x32_bf16(ahf[mi], bhf[ni], acc[mi][ni], 0, 0, 0);
                acc[mi][ni] = __builtin_amdgcn_mfma_f32_16x16x32_bf16(ahf[mi], blf[ni], acc[mi][ni], 0, 0, 0);
                acc[mi][ni] = __builtin_amdgcn_mfma_f32_16x16x32_bf16(alf[mi], bhf[ni], acc[mi][ni], 0, 0, 0);
            }
        }
        if (c0 + 32 < Cs){
            #pragma unroll
            for (int i = 0; i < 4; i++){ ahf[i] = nah[i]; alf[i] = nal[i]; }
        }
    }

    // D layout: o = wo + mi*16 + 4*(lane>>4) + r,  l = wl + ni*16 + (lane&15)
    if (OM == 0){
        if (Y && (l0 + 128 <= Lwrite)){
            #pragma unroll
            for (int mi = 0; mi < 4; mi++){
                #pragma unroll
                for (int ni = 0; ni < 4; ni++){
                    int o = o0 + wo + mi * 16 + 4 * (lane >> 4);
                    int l = l0 + wl + ni * 16 + (lane & 15);
                    *(float4*)(Y + (size_t)l * FF + o) =
                        make_float4(acc[mi][ni][0], acc[mi][ni][1], acc[mi][ni][2], acc[mi][ni][3]);
                }
            }
        }
    }
    if (stats){
        int slot_s = blockIdx.x & (NSLOT - 1);
        double* sp = stats + (size_t)slot_s * FF * 2;
        #pragma unroll
        for (int mi = 0; mi < 4; mi++){
            float s1[4] = {0,0,0,0}, s2[4] = {0,0,0,0};
            #pragma unroll
            for (int ni = 0; ni < 4; ni++){
                #pragma unroll
                for (int r = 0; r < 4; r++){
                    float v = acc[mi][ni][r];
                    s1[r] += v; s2[r] += v * v;
                }
            }
            #pragma unroll
            for (int off = 8; off; off >>= 1){
                #pragma unroll
                for (int r = 0; r < 4; r++){
                    s1[r] += __shfl_down(s1[r], off, 16);
                    s2[r] += __shfl_down(s2[r], off, 16);
                }
            }
            if ((lane & 15) == 0){
                int o = o0 + wo + mi * 16 + 4 * (lane >> 4);
                #pragma unroll
                for (int r = 0; r < 4; r++){
                    atomicAdd(&sp[2 * (o + r)],     (double)s1[r]);
                    atomicAdd(&sp[2 * (o + r) + 1], (double)s2[r]);
                }
            }
        }
    }
    if (OM == 1){
        // raw per-q-group max/min over k: q-group g covers l = wl + g*32 + [0,32)
        #pragma unroll
        for (int mi = 0; mi < 4; mi++){
            #pragma unroll
            for (int g = 0; g < 2; g++){
                float vmx[4], vmn[4];
                #pragma unroll
                for (int r = 0; r < 4; r++){
                    float a0 = acc[mi][2*g][r], a1 = acc[mi][2*g+1][r];
                    vmx[r] = fmaxf(a0, a1); vmn[r] = fminf(a0, a1);
                }
                #pragma unroll
                for (int off = 8; off; off >>= 1){
                    #pragma unroll
                    for (int r = 0; r < 4; r++){
                        vmx[r] = fmaxf(vmx[r], __shfl_down(vmx[r], off, 16));
                        vmn[r] = fminf(vmn[r], __shfl_down(vmn[r], off, 16));
                    }
                }
                if ((lane & 15) == 0){
                    int qg = (Lbase + l0 + wl) / 32 + g;
                    #pragma unroll
                    for (int r = 0; r < 4; r++){
                        int o = o0 + wo + mi * 16 + 4 * (lane >> 4) + r;
                        y3mx[(size_t)qg * FF + o] = vmx[r];
                        y3mn[(size_t)qg * FF + o] = vmn[r];
                    }
                }
            }
        }
    }
}

// ---------------- finalize BN ----------------
__global__ void k_finL(const double* __restrict__ stats, const float* __restrict__ g,
                       const float* __restrict__ bt, float* __restrict__ scb){
    int o = blockIdx.x * 256 + threadIdx.x;
    double s = 0.0, s2 = 0.0;
    for (int k = 0; k < NSLOT; k++){
        s  += stats[((size_t)k * FF + o) * 2];
        s2 += stats[((size_t)k * FF + o) * 2 + 1];
    }
    double mean = s / (double)LTOT;
    double var  = s2 / (double)LTOT - mean * mean;
    if (!(var > 0.0)) var = 0.0;
    double rs = 1.0 / sqrt(var + 1e-5);
    double sc = rs * (double)g[o];
    double bi = (double)bt[o] - mean * sc;
    float scf = (float)sc, bif = (float)bi;
    if (!isfinite(scf) || !isfinite(bif)){ scf = 1.f; bif = 0.f; }
    scb[o] = scf;
    scb[FF + o] = bif;
}

// ---------------- y1 stats ----------------
__global__ __launch_bounds__(256) void k_y1stats(const float* __restrict__ z,
                                                 const int* __restrict__ idx2,
                                                 const float4* __restrict__ xyzd,
                                                 const float4* __restrict__ w1xp,
                                                 double* __restrict__ stats){
    int tid = threadIdx.x, bid = blockIdx.x;
    int o1 = tid, o2 = tid + 256;
    float4 wa = w1xp[o1], wb = w1xp[o2];
    double s1a=0, s2a=0, s1b=0, s2b=0;
    for (int p = 0; p < LTOT/2048; p++){
        int l = bid + p * 2048;
        int r = idx2[l];
        float4 d = xyzd[l];
        const float* zr = z + (size_t)r * FF;
        float ya = zr[o1] + d.x*wa.x + d.y*wa.y + d.z*wa.z;
        float yb = zr[o2] + d.x*wb.x + d.y*wb.y + d.z*wb.z;
        s1a += ya; s2a += (double)ya*ya;
        s1b += yb; s2b += (double)yb*yb;
    }
    int slot = bid & (NSLOT - 1);
    double* sp = stats + (size_t)slot * FF * 2;
    atomicAdd(&sp[2*o1],   s1a); atomicAdd(&sp[2*o1+1], s2a);
    atomicAdd(&sp[2*o2],   s1b); atomicAdd(&sp[2*o2+1], s2b);
}

// ---------------- BN3 + final selection from stored max/min ----------------
__global__ __launch_bounds__(256) void k_bn3max(const float* __restrict__ mx,
                                                const float* __restrict__ mn,
                                                const float* __restrict__ scb,
                                                float* __restrict__ out){
    int t = blockIdx.x * 256 + threadIdx.x;
    int o = t & (FF - 1);
    float sc = scb[o], bi = scb[FF + o];
    float v = sc >= 0.f ? mx[t] : mn[t];
    out[t] = fmaxf(sc * v + bi, 0.f);
}

// ---------------- stage diagnostics (float sentinel, fires only on unhealthy) ----------------
__global__ __launch_bounds__(256) void k_diag(const float* __restrict__ ff,
                                              const float* __restrict__ w1f,
                                              const float* __restrict__ featT,
                                              const float* __restrict__ z,
                                              const float* __restrict__ xyzdf,
                                              const float* __restrict__ scb1,
                                              const float* __restrict__ scbL2,
                                              const float* __restrict__ scbL3,
                                              const float* __restrict__ y3,
                                              float* __restrict__ out){
    __shared__ float red[4];
    int tid = threadIdx.x;
    int bad = 0, isn = 0;
    const float* arr[9] = {ff, w1f, featT, z, xyzdf, scb1, scbL2, scbL3, y3};
    const int   len[9] = {4096, 4096, 8192, 8192, 4096, 1024, 1024, 1024, 8192};
    for (int k = 0; k < 9; k++){
        float s = 0.f;
        const float* a = arr[k];
        for (int i = tid; i < len[k]; i += 256) s += fabsf(a[i]);
        for (int off = 32; off; off >>= 1) s += __shfl_down(s, off);
        if ((tid & 63) == 0) red[tid >> 6] = s;
        __syncthreads();
        float t = red[0] + red[1] + red[2] + red[3];
        __syncthreads();
        if (bad == 0 && !(t > 1e-6f && t < 1e15f)){
            bad = k + 1;
            isn = isfinite(t) ? 0 : 1;
        }
    }
    if (tid == 0 && bad) out[0] = 512.f * bad + 256.f * isn;
}

extern "C" void kernel_launch(void* const* d_in, const int* in_sizes, int n_in,
                              void* d_out, int out_size, void* d_ws, size_t ws_size,
                              hipStream_t stream) {
    static const int NSZ[19] = {12288, 1048576, 196608, 16777216, 32768, 128, 128,
                                384, 3, 3, 132608, 512, 512, 262144, 512, 512,
                                262144, 512, 512};
    float* out = (float*)d_out;   // OUTPUT IS FLOAT32

    char* w = (char*)d_ws;
    size_t off = 0;
    auto take = [&](size_t bytes)->size_t{
        size_t r = off; off += (bytes + 255) & ~(size_t)255; return r;
    };
    size_t o_stats1  = take(256 * 4);
    size_t o_stats2  = take(8 * 4);
    size_t o_statsA  = take((size_t)NSLOT * FF * 2 * 8);
    size_t o_statsL2 = take((size_t)NSLOT * FF * 2 * 8);
    size_t o_statsL3 = take((size_t)NSLOT * FF * 2 * 8);
    size_t zero_end  = off;
    size_t o_flags   = take(19 * 4);
    size_t o_cv[19];
    for (int i = 0; i < 19; i++){
        if (i == 3){ o_cv[i] = 0; continue; }
        o_cv[i] = take((size_t)NSZ[i] * 4);
    }
    size_t o_scb2    = take(8 * 4);
    size_t o_scb1    = take(FF * 2 * 4);
    size_t o_scbL2   = take(FF * 2 * 4);
    size_t o_scbL3   = take(FF * 2 * 4);
    size_t o_h1      = take((size_t)BB * O1 * MM * 4);
    size_t o_h2      = take((size_t)BB * 3 * MM * 4);
    size_t o_nxyz    = take((size_t)BB * MM * 3 * 4);
    size_t o_idx     = take((size_t)LTOT * 4);
    size_t o_idx2    = take((size_t)LTOT * 4);
    size_t o_xyzd    = take((size_t)LTOT * 16);
    size_t o_w1h     = take((size_t)FF * CC * 2);
    size_t o_w1l     = take((size_t)FF * CC * 2);
    size_t o_w2h     = take((size_t)FF * FF * 2);
    size_t o_w2l     = take((size_t)FF * FF * 2);
    size_t o_w3h     = take((size_t)FF * FF * 2);
    size_t o_w3l     = take((size_t)FF * FF * 2);
    size_t o_w1xp    = take((size_t)FF * 16);
    size_t o_y3mx    = take((size_t)BB * MM * FF * 4);    // 8.4 MB
    size_t o_y3mn    = take((size_t)BB * MM * FF * 4);    // 8.4 MB
    size_t o_z       = take((size_t)BB * NN * FF * 4);    // 134 MB
    size_t o_featT   = take((size_t)BB * NN * CC * 4);    // 67 MB, dead after z-GEMM
    (void)n_in; (void)in_sizes; (void)out_size;

    // adaptive t2 chunk storage in [o_featT, ws_size)
    const size_t chb = (size_t)CH * FF * 4;               // 33.5 MB per chunk
    size_t avail = ws_size > o_featT ? ws_size - o_featT : 0;
    int S; bool full;
    if (avail >= (size_t)NCH2 * chb){ S = NCH2; full = true; }
    else {
        long s = (long)(avail / chb) - 1;                 // reserve 1 chunk for scratch
        if (s < 0) s = 0; if (s > NCH2 - 1) s = NCH2 - 1;
        S = (int)s; full = false;
    }
    const int Lwrite = S * CH;

    float*  stats1  = (float*) (w + o_stats1);
    float*  stats2  = (float*) (w + o_stats2);
    double* statsA  = (double*)(w + o_statsA);
    double* statsL2 = (double*)(w + o_statsL2);
    double* statsL3 = (double*)(w + o_statsL3);
    int*    flags   = (int*)   (w + o_flags);
    float*  scb2    = (float*) (w + o_scb2);
    float*  scb1    = (float*) (w + o_scb1);
    float*  scbL2   = (float*) (w + o_scbL2);
    float*  scbL3   = (float*) (w + o_scbL3);
    float*  h1      = (float*) (w + o_h1);
    float*  h2      = (float*) (w + o_h2);
    float*  nxyz    = (float*) (w + o_nxyz);
    int*    idxbuf  = (int*)   (w + o_idx);
    int*    idx2    = (int*)   (w + o_idx2);
    float4* xyzd    = (float4*)(w + o_xyzd);
    unsigned short* w1h = (unsigned short*)(w + o_w1h);
    unsigned short* w1l = (unsigned short*)(w + o_w1l);
    unsigned short* w2h = (unsigned short*)(w + o_w2h);
    unsigned short* w2l = (unsigned short*)(w + o_w2l);
    unsigned short* w3h = (unsigned short*)(w + o_w3h);
    unsigned short* w3l = (unsigned short*)(w + o_w3l);
    float4* w1xp    = (float4*)(w + o_w1xp);
    float*  y3mx    = (float*) (w + o_y3mx);
    float*  y3mn    = (float*) (w + o_y3mn);
    float*  z       = (float*) (w + o_z);
    float*  featT   = (float*) (w + o_featT);
    float*  t2scr   = featT;                                        // scratch chunk
    float*  t2store = full ? featT : featT + (size_t)CH * FF;       // stored rows [0, S*CH)

    hipMemsetAsync(w, 0, zero_end, stream);

    // batched detect + convert (2 dispatches instead of 37)
    CvtA ca;
    unsigned cum = 0;
    for (int i = 0; i < 19; i++){
        ca.src[i]  = d_in[i];
        ca.nsz[i]  = NSZ[i];
        ca.dstF[i] = (unsigned)(o_cv[i] / 4);
        ca.cum[i]  = cum;
        if (i != 3) cum += (unsigned)((NSZ[i] + 255) & ~255);
    }
    ca.cum[19] = cum;
    // fix cum to be start-of-input (recompute properly)
    {
        unsigned c2 = 0;
        for (int i = 0; i < 19; i++){
            ca.cum[i] = c2;
            if (i != 3) c2 += (unsigned)((NSZ[i] + 255) & ~255);
        }
        ca.cum[19] = c2;
    }
    k_det19<<<19, 64, 0, stream>>>(ca, flags);
    k_cvt19<<<ca.cum[19] / 256, 256, 0, stream>>>(ca, flags, (float*)w);

    float* cv[19];
    for (int i = 0; i < 19; i++) cv[i] = (i == 3) ? nullptr : (float*)(w + o_cv[i]);
    float* fx = cv[0], *ffp = cv[1], *bx = cv[2];
    float* sw1f = cv[4], *sg1f = cv[5], *sb1f = cv[6];
    float* sw2f = cv[7], *sg2f = cv[8], *sb2f = cv[9];
    float* w1f = cv[10], *g1f = cv[11], *b1f = cv[12];
    float* w2f = cv[13], *g2f = cv[14], *b2f = cv[15];
    float* w3f = cv[16], *g3f = cv[17], *b3f = cv[18];

    k_mlp1   <<<2048, 256, 0, stream>>>(sw1f, ffp, h1, stats1);
    k_bn1mlp2<<<48,   256, 0, stream>>>(h1, stats1, sg1f, sb1f, sw2f, h2, stats2);
    k_fin2   <<<1,    64,  0, stream>>>(stats2, sg2f, sb2f, scb2);
    k_ballq  <<<BB*MM/4, 256, 0, stream>>>(fx, h2, scb2, bx, nxyz, idxbuf);
    k_xyzd   <<<LTOT/256, 256, 0, stream>>>(idxbuf, bx, nxyz, idx2, xyzd);
    k_transp <<<BB*(CC/32)*(NN/32), 256, 0, stream>>>(d_in[3], flags + 3, featT);
    k_wpack  <<<(FF*CC)/256, 256, 0, stream>>>(w1f, 259, 3, CC, w1h, w1l);
    k_wpack  <<<(FF*FF)/256, 256, 0, stream>>>(w2f, FF, 0, FF, w2h, w2l);
    k_wpack  <<<(FF*FF)/256, 256, 0, stream>>>(w3f, FF, 0, FF, w3h, w3l);
    k_w1xyz  <<<2, 256, 0, stream>>>(w1f, w1xp);

    // z = featT @ w1^T : (65536 x 256) x (512 x 256)^T -> 65536 x 512
    k_gemm<0,0><<<4 * (BB*NN/128), 256, 0, stream>>>(w1h, w1l, featT, CC, nullptr,
            nullptr, nullptr, nullptr, 0, z, BB*NN, nullptr, nullptr, nullptr);

    k_y1stats<<<2048, 256, 0, stream>>>(z, idx2, xyzd, w1xp, statsA);
    k_finL  <<<2, 256, 0, stream>>>(statsA, g1f, b1f, scb1);

    const int GFULL = 4 * (LTOT/128);   // 4096
    const int GCH   = 4 * (CH/128);     // 512

    // pass 1: full gemm2 (y1 fused) -> statsL2; store t2 rows [0, S*CH)
    k_gemm<1,0><<<GFULL, 256, 0, stream>>>(w2h, w2l, z, FF, scb1,
            idx2, xyzd, w1xp, 0, t2store, Lwrite, nullptr, nullptr, statsL2);
    k_finL <<<2, 256, 0, stream>>>(statsL2, g2f, b2f, scbL2);

    // pass 2: gemm3 over all rows exactly once -> statsL3 + raw per-q max/min
    if (S > 0){
        k_gemm<0,1><<<S * GCH, 256, 0, stream>>>(w3h, w3l, t2store, FF, scbL2,
                nullptr, nullptr, nullptr, 0, nullptr, 0, y3mx, y3mn, statsL3);
    }
    for (int c = S; c < NCH2; c++){
        k_gemm<1,0><<<GCH, 256, 0, stream>>>(w2h, w2l, z, FF, scb1,
                idx2, xyzd, w1xp, c*CH, t2scr, CH, nullptr, nullptr, nullptr);
        k_gemm<0,1><<<GCH, 256, 0, stream>>>(w3h, w3l, t2scr, FF, scbL2,
                nullptr, nullptr, nullptr, c*CH, nullptr, 0, y3mx, y3mn, statsL3);
    }
    k_finL <<<2, 256, 0, stream>>>(statsL3, g3f, b3f, scbL3);

    // pass 3: BN3 + select + relu (exact: relu(sc*v+bi) monotone in v per sign of sc)
    k_bn3max<<<(BB*MM*FF)/256, 256, 0, stream>>>(y3mx, y3mn, scbL3, out);

    k_diag<<<1, 256, 0, stream>>>(ffp, w1f, t2scr, z, (const float*)xyzd,
                                  scb1, scbL2, scbL3, y3mx, out);
}